// Round 1
// baseline (3300.866 us; speedup 1.0000x reference)
//
#include <hip/hip_runtime.h>
#include <math.h>

// Problem constants (from reference)
#define NN 5000
#define NE 50000
#define NEE 55000   // edges + self loops
#define NG 8
#define NH 4

// ---------------- utility device functions ----------------

__device__ inline float waveSum(float v) {
    #pragma unroll
    for (int o = 32; o > 0; o >>= 1) v += __shfl_xor(v, o, 64);
    return v;
}
__device__ inline float waveMax(float v) {
    #pragma unroll
    for (int o = 32; o > 0; o >>= 1) v = fmaxf(v, __shfl_xor(v, o, 64));
    return v;
}

// monotone float<->uint encoding for atomicMax on signed floats
__device__ inline unsigned int fenc(float f) {
    unsigned int u = __float_as_uint(f);
    return (u & 0x80000000u) ? ~u : (u | 0x80000000u);
}
__device__ inline float fdec(unsigned int u) {
    u = (u & 0x80000000u) ? (u & 0x7fffffffu) : ~u;
    return __uint_as_float(u);
}

// ---------------- GEMM: C = A @ B + bias ----------------
// A: (Nrows, K) row-major, B: (K, M) row-major, bias: (M), C: (Nrows, M)
// BM=128, BN=64, BK=16, 256 threads, 8x4 micro-tile per thread.
#define GBM 128
#define GBN 64
#define GBK 16

__global__ __launch_bounds__(256) void gemm_bias(
    const float* __restrict__ A, const float* __restrict__ B,
    const float* __restrict__ bias, float* __restrict__ C,
    int Nrows, int K, int M)
{
    __shared__ float As[GBK][GBM + 4];  // pad keeps b128 reads aligned + conflict-free
    __shared__ float Bs[GBK][GBN + 4];
    const int tid = threadIdx.x;
    const int tx = tid & 15;   // col group (16 * 4 = 64 cols)
    const int ty = tid >> 4;   // row group (16 * 8 = 128 rows)
    const int rowBase = blockIdx.y * GBM;
    const int colBase = blockIdx.x * GBN;

    const int ar = tid >> 2;          // 0..63
    const int ak = (tid & 3) << 2;    // 0,4,8,12
    const int bk = tid >> 4;          // 0..15
    const int bc = (tid & 15) << 2;   // 0..60

    float acc[8][4];
    #pragma unroll
    for (int i = 0; i < 8; ++i)
        #pragma unroll
        for (int j = 0; j < 4; ++j) acc[i][j] = 0.f;

    for (int k0 = 0; k0 < K; k0 += GBK) {
        #pragma unroll
        for (int half = 0; half < 2; ++half) {
            int r = ar + half * 64;
            int grow = rowBase + r;
            float4 v = make_float4(0.f, 0.f, 0.f, 0.f);
            if (grow < Nrows) v = *(const float4*)(A + (size_t)grow * K + k0 + ak);
            As[ak + 0][r] = v.x; As[ak + 1][r] = v.y;
            As[ak + 2][r] = v.z; As[ak + 3][r] = v.w;
        }
        {
            float4 v = *(const float4*)(B + (size_t)(k0 + bk) * M + colBase + bc);
            *(float4*)&Bs[bk][bc] = v;
        }
        __syncthreads();
        #pragma unroll
        for (int k = 0; k < GBK; ++k) {
            float a[8], b[4];
            *(float4*)&a[0] = *(const float4*)&As[k][ty * 8];
            *(float4*)&a[4] = *(const float4*)&As[k][ty * 8 + 4];
            *(float4*)&b[0] = *(const float4*)&Bs[k][tx * 4];
            #pragma unroll
            for (int i = 0; i < 8; ++i)
                #pragma unroll
                for (int j = 0; j < 4; ++j)
                    acc[i][j] = fmaf(a[i], b[j], acc[i][j]);
        }
        __syncthreads();
    }

    float4 bv = *(const float4*)(bias + colBase + tx * 4);
    #pragma unroll
    for (int i = 0; i < 8; ++i) {
        int grow = rowBase + ty * 8 + i;
        if (grow < Nrows) {
            float4 o;
            o.x = acc[i][0] + bv.x; o.y = acc[i][1] + bv.y;
            o.z = acc[i][2] + bv.z; o.w = acc[i][3] + bv.w;
            *(float4*)(C + (size_t)grow * M + colBase + tx * 4) = o;
        }
    }
}

// ---------------- edge / graph kernels ----------------

__global__ void k_build_edges(const int* __restrict__ ei, int* __restrict__ src,
                              int* __restrict__ dst) {
    int i = blockIdx.x * 256 + threadIdx.x;
    if (i < NE) { src[i] = ei[i]; dst[i] = ei[NE + i]; }
    else if (i < NEE) { src[i] = i - NE; dst[i] = i - NE; }
}

__global__ void k_zero32(unsigned int* __restrict__ p, int n) {
    int i = blockIdx.x * 256 + threadIdx.x;
    if (i < n) p[i] = 0u;
}

__global__ void k_count(const int* __restrict__ dst, int* __restrict__ cnt) {
    int i = blockIdx.x * 256 + threadIdx.x;
    if (i < NEE) atomicAdd(&cnt[dst[i]], 1);
}

// single-block scan: offsets + cursor copy; off has NN+1 entries
__global__ __launch_bounds__(256) void k_scan(const int* __restrict__ cnt,
                                              int* __restrict__ off, int* __restrict__ cur) {
    __shared__ int partial[256];
    __shared__ int ppre[257];
    int t = threadIdx.x;
    const int chunk = (NN + 255) / 256;
    int lo = t * chunk, hi = min(NN, (t + 1) * chunk);
    int s = 0;
    for (int i = lo; i < hi; ++i) s += cnt[i];
    partial[t] = s;
    __syncthreads();
    if (t == 0) {
        int acc = 0;
        for (int i = 0; i < 256; ++i) { ppre[i] = acc; acc += partial[i]; }
        ppre[256] = acc;
    }
    __syncthreads();
    int acc = ppre[t];
    for (int i = lo; i < hi; ++i) { off[i] = acc; cur[i] = acc; acc += cnt[i]; }
    if (t == 0) off[NN] = ppre[256];
}

__global__ void k_fill(const int* __restrict__ dst, int* __restrict__ cur,
                       int* __restrict__ elist) {
    int e = blockIdx.x * 256 + threadIdx.x;
    if (e < NEE) { int p = atomicAdd(&cur[dst[e]], 1); elist[p] = e; }
}

// per-edge attention scores: s[e,h] = sum_c lrelu(xl[src,h,c]+xr[dst,h,c])*att[h,c]
__global__ __launch_bounds__(256) void k_edge_score(
    const float* __restrict__ xl, const float* __restrict__ xr,
    const float* __restrict__ att, const int* __restrict__ src,
    const int* __restrict__ dst, float* __restrict__ s, int C)
{
    int e = blockIdx.x;
    int h = threadIdx.x >> 6;
    int lane = threadIdx.x & 63;
    int se = src[e], de = dst[e];
    const float* pl = xl + (size_t)se * (NH * C) + h * C;
    const float* pr = xr + (size_t)de * (NH * C) + h * C;
    const float* pa = att + h * C;
    float acc = 0.f;
    for (int c = lane; c < C; c += 64) {
        float v = pl[c] + pr[c];
        v = v > 0.f ? v : 0.2f * v;
        acc = fmaf(v, pa[c], acc);
    }
    acc = waveSum(acc);
    if (lane == 0) s[(size_t)e * NH + h] = acc;
}

__global__ void k_init_md(unsigned int* __restrict__ mEnc, float* __restrict__ den) {
    int i = blockIdx.x * 256 + threadIdx.x;
    if (i < NN * NH) { mEnc[i] = 0u; den[i] = 0.f; }
}

__global__ void k_seg_max(const float* __restrict__ s, const int* __restrict__ dst,
                          unsigned int* __restrict__ mEnc) {
    int i = blockIdx.x * 256 + threadIdx.x;
    if (i >= NEE * NH) return;
    int e = i >> 2, h = i & 3;
    atomicMax(&mEnc[dst[e] * NH + h], fenc(s[i]));
}

__global__ void k_exp_den(float* __restrict__ s, const int* __restrict__ dst,
                          const unsigned int* __restrict__ mEnc, float* __restrict__ den) {
    int i = blockIdx.x * 256 + threadIdx.x;
    if (i >= NEE * NH) return;
    int e = i >> 2, h = i & 3;
    float m = fdec(mEnc[dst[e] * NH + h]);
    float ex = expf(s[i] - m);
    s[i] = ex;
    atomicAdd(&den[dst[e] * NH + h], ex);
}

__global__ void k_alpha(float* __restrict__ s, const int* __restrict__ dst,
                        const float* __restrict__ den) {
    int i = blockIdx.x * 256 + threadIdx.x;
    if (i >= NEE * NH) return;
    int e = i >> 2, h = i & 3;
    s[i] = s[i] / (den[dst[e] * NH + h] + 1e-16f);
}

// out[n,c] = relu( mean_h sum_{e->n} alpha[e,h]*xl[src,h,c] + bias[c] )
__global__ __launch_bounds__(256) void k_aggregate(
    const float* __restrict__ xl, const float* __restrict__ alpha,
    const int* __restrict__ eoff, const int* __restrict__ elist,
    const int* __restrict__ src, const float* __restrict__ bias,
    float* __restrict__ out, int C)
{
    int n = blockIdx.x;
    int start = eoff[n], end = eoff[n + 1];
    for (int c = threadIdx.x; c < C; c += 256) {
        float a0 = 0.f, a1 = 0.f, a2 = 0.f, a3 = 0.f;
        for (int j = start; j < end; ++j) {
            int e = elist[j];
            int sn = src[e];
            const float* pl = xl + (size_t)sn * NH * C;
            const float* pa = alpha + (size_t)e * NH;
            a0 = fmaf(pa[0], pl[c], a0);
            a1 = fmaf(pa[1], pl[C + c], a1);
            a2 = fmaf(pa[2], pl[2 * C + c], a2);
            a3 = fmaf(pa[3], pl[3 * C + c], a3);
        }
        float v = (a0 + a1 + a2 + a3) * 0.25f + bias[c];
        out[(size_t)n * C + c] = v > 0.f ? v : 0.f;
    }
}

// ---------------- gate + pool + MLP ----------------

// g[n] = relu(x[n] @ Wg0 + bg0) @ Wg1 + bg1   (per-node block of 128 threads)
__global__ __launch_bounds__(128) void k_gate(
    const float* __restrict__ x, const float* __restrict__ Wg0,
    const float* __restrict__ bg0, const float* __restrict__ Wg1,
    const float* __restrict__ bg1, float* __restrict__ g)
{
    int n = blockIdx.x;
    int t = threadIdx.x;
    __shared__ float xs[256];
    __shared__ float wsum[2];
    const float* xp = x + (size_t)n * 256;
    xs[t] = xp[t]; xs[t + 128] = xp[t + 128];
    __syncthreads();
    float acc = bg0[t];
    for (int k = 0; k < 256; ++k) acc = fmaf(xs[k], Wg0[k * 128 + t], acc);
    acc = acc > 0.f ? acc : 0.f;
    float prod = acc * Wg1[t];
    prod = waveSum(prod);
    if ((t & 63) == 0) wsum[t >> 6] = prod;
    __syncthreads();
    if (t == 0) g[n] = wsum[0] + wsum[1] + bg1[0];
}

__global__ void k_group_bounds(const int* __restrict__ batch, int* __restrict__ gstart,
                               int* __restrict__ gend) {
    int n = blockIdx.x * 256 + threadIdx.x;
    if (n >= NN) return;
    int b = batch[n];
    if (n == 0 || batch[n - 1] != b) gstart[b] = n;
    if (n == NN - 1 || batch[n + 1] != b) gend[b] = n + 1;
}

// block per group: softmax over contiguous node range, weighted sum of x
__global__ __launch_bounds__(256) void k_pool(
    const float* __restrict__ x, const float* __restrict__ g,
    const int* __restrict__ gstart, const int* __restrict__ gend,
    float* __restrict__ hpool)
{
    int gi = blockIdx.x;
    int t = threadIdx.x;
    int s0 = gstart[gi], e0 = gend[gi];
    __shared__ float red[4];
    // pass 1: max
    float mx = -1e30f;
    for (int n = s0 + t; n < e0; n += 256) mx = fmaxf(mx, g[n]);
    float wm = waveMax(mx);
    if ((t & 63) == 0) red[t >> 6] = wm;
    __syncthreads();
    float m = fmaxf(fmaxf(red[0], red[1]), fmaxf(red[2], red[3]));
    __syncthreads();
    // pass 2: den
    float sm = 0.f;
    for (int n = s0 + t; n < e0; n += 256) sm += expf(g[n] - m);
    sm = waveSum(sm);
    if ((t & 63) == 0) red[t >> 6] = sm;
    __syncthreads();
    float den = red[0] + red[1] + red[2] + red[3] + 1e-16f;
    // pass 3: thread t owns channel t
    float acc = 0.f;
    for (int n = s0; n < e0; ++n) {
        float w = expf(g[n] - m) / den;
        acc = fmaf(w, x[(size_t)n * 256 + t], acc);
    }
    hpool[gi * 256 + t] = acc;
}

// single-block MLP head: (8,256)->128->64->32->16->1
__global__ __launch_bounds__(256) void k_mlp(
    const float* __restrict__ hpool,
    const float* __restrict__ Wm0, const float* __restrict__ bm0,
    const float* __restrict__ Wm1, const float* __restrict__ bm1,
    const float* __restrict__ Wm2, const float* __restrict__ bm2,
    const float* __restrict__ Wm3, const float* __restrict__ bm3,
    const float* __restrict__ Wm4, const float* __restrict__ bm4,
    float* __restrict__ out)
{
    __shared__ float bufA[8 * 256];
    __shared__ float bufB[8 * 128];
    int t = threadIdx.x;
    for (int i = t; i < 8 * 256; i += 256) bufA[i] = hpool[i];
    __syncthreads();
    for (int i = t; i < 8 * 128; i += 256) {
        int r = i >> 7, c = i & 127;
        float acc = bm0[c];
        for (int k = 0; k < 256; ++k) acc = fmaf(bufA[r * 256 + k], Wm0[k * 128 + c], acc);
        bufB[i] = fmaxf(acc, 0.f);
    }
    __syncthreads();
    for (int i = t; i < 8 * 64; i += 256) {
        int r = i >> 6, c = i & 63;
        float acc = bm1[c];
        for (int k = 0; k < 128; ++k) acc = fmaf(bufB[r * 128 + k], Wm1[k * 64 + c], acc);
        bufA[i] = fmaxf(acc, 0.f);
    }
    __syncthreads();
    for (int i = t; i < 8 * 32; i += 256) {
        int r = i >> 5, c = i & 31;
        float acc = bm2[c];
        for (int k = 0; k < 64; ++k) acc = fmaf(bufA[r * 64 + k], Wm2[k * 32 + c], acc);
        bufB[i] = fmaxf(acc, 0.f);
    }
    __syncthreads();
    for (int i = t; i < 8 * 16; i += 256) {
        int r = i >> 4, c = i & 15;
        float acc = bm3[c];
        for (int k = 0; k < 32; ++k) acc = fmaf(bufB[r * 32 + k], Wm3[k * 16 + c], acc);
        bufA[i] = fmaxf(acc, 0.f);
    }
    __syncthreads();
    if (t < 8) {
        float acc = bm4[0];
        for (int k = 0; k < 16; ++k) acc = fmaf(bufA[t * 16 + k], Wm4[k], acc);
        out[t] = acc;
    }
}

// ---------------- host orchestration ----------------

static void run_gat_layer(const float* xin, int K, int C,
                          const float* Wl, const float* bl,
                          const float* Wr, const float* br,
                          const float* att, const float* bias,
                          float* xl, float* xr, float* sb,
                          unsigned int* mEnc, float* den,
                          const int* srcA, const int* dstA,
                          const int* eoff, const int* elist,
                          float* xout, hipStream_t stream)
{
    int HC = NH * C;
    dim3 ggrid(HC / GBN, (NN + GBM - 1) / GBM);
    gemm_bias<<<ggrid, 256, 0, stream>>>(xin, Wl, bl, xl, NN, K, HC);
    gemm_bias<<<ggrid, 256, 0, stream>>>(xin, Wr, br, xr, NN, K, HC);
    k_edge_score<<<NEE, 256, 0, stream>>>(xl, xr, att, srcA, dstA, sb, C);
    k_init_md<<<(NN * NH + 255) / 256, 256, 0, stream>>>(mEnc, den);
    int eb = (NEE * NH + 255) / 256;
    k_seg_max<<<eb, 256, 0, stream>>>(sb, dstA, mEnc);
    k_exp_den<<<eb, 256, 0, stream>>>(sb, dstA, mEnc, den);
    k_alpha<<<eb, 256, 0, stream>>>(sb, dstA, den);
    k_aggregate<<<NN, 256, 0, stream>>>(xl, sb, eoff, elist, srcA, bias, xout, C);
}

extern "C" void kernel_launch(void* const* d_in, const int* in_sizes, int n_in,
                              void* d_out, int out_size, void* d_ws, size_t ws_size,
                              hipStream_t stream) {
    const float* x      = (const float*)d_in[0];
    const int* ei       = (const int*)d_in[1];
    const int* batch    = (const int*)d_in[2];
    const float* Wl1 = (const float*)d_in[3];  const float* bl1 = (const float*)d_in[4];
    const float* Wr1 = (const float*)d_in[5];  const float* br1 = (const float*)d_in[6];
    const float* att1= (const float*)d_in[7];  const float* b1  = (const float*)d_in[8];
    const float* Wl2 = (const float*)d_in[9];  const float* bl2 = (const float*)d_in[10];
    const float* Wr2 = (const float*)d_in[11]; const float* br2 = (const float*)d_in[12];
    const float* att2= (const float*)d_in[13]; const float* b2  = (const float*)d_in[14];
    const float* Wl3 = (const float*)d_in[15]; const float* bl3 = (const float*)d_in[16];
    const float* Wr3 = (const float*)d_in[17]; const float* br3 = (const float*)d_in[18];
    const float* att3= (const float*)d_in[19]; const float* b3  = (const float*)d_in[20];
    const float* Wm0 = (const float*)d_in[21]; const float* bm0 = (const float*)d_in[22];
    const float* Wm1 = (const float*)d_in[23]; const float* bm1 = (const float*)d_in[24];
    const float* Wm2 = (const float*)d_in[25]; const float* bm2 = (const float*)d_in[26];
    const float* Wm3 = (const float*)d_in[27]; const float* bm3 = (const float*)d_in[28];
    const float* Wm4 = (const float*)d_in[29]; const float* bm4 = (const float*)d_in[30];
    const float* Wg0 = (const float*)d_in[31]; const float* bg0 = (const float*)d_in[32];
    const float* Wg1 = (const float*)d_in[33]; const float* bg1 = (const float*)d_in[34];
    float* out = (float*)d_out;

    // workspace carve (floats)
    float* ws = (float*)d_ws;
    size_t o = 0;
    float* xl    = ws + o; o += (size_t)NN * 4096;
    float* xr    = ws + o; o += (size_t)NN * 4096;
    float* x1    = ws + o; o += (size_t)NN * 1024;
    float* x2    = ws + o; o += (size_t)NN * 512;
    float* x3    = ws + o; o += (size_t)NN * 256;
    float* sb    = ws + o; o += (size_t)NEE * NH;
    unsigned int* mEnc = (unsigned int*)(ws + o); o += NN * NH;
    float* den   = ws + o; o += NN * NH;
    int* srcA    = (int*)(ws + o); o += NEE;
    int* dstA    = (int*)(ws + o); o += NEE;
    int* cnt     = (int*)(ws + o); o += NN;
    int* eoff    = (int*)(ws + o); o += NN + 1;
    int* cur     = (int*)(ws + o); o += NN;
    int* elist   = (int*)(ws + o); o += NEE;
    float* g     = ws + o; o += NN;
    int* gstart  = (int*)(ws + o); o += NG;
    int* gend    = (int*)(ws + o); o += NG;
    float* hpool = ws + o; o += NG * 256;

    // build CSR by dst (recomputed every call; ws is re-poisoned)
    int ebB = (NEE + 255) / 256;
    k_build_edges<<<ebB, 256, 0, stream>>>(ei, srcA, dstA);
    k_zero32<<<(NN + 255) / 256, 256, 0, stream>>>((unsigned int*)cnt, NN);
    k_count<<<ebB, 256, 0, stream>>>(dstA, cnt);
    k_scan<<<1, 256, 0, stream>>>(cnt, eoff, cur);
    k_fill<<<ebB, 256, 0, stream>>>(dstA, cur, elist);

    // three GATv2 layers
    run_gat_layer(x,  1536, 1024, Wl1, bl1, Wr1, br1, att1, b1,
                  xl, xr, sb, mEnc, den, srcA, dstA, eoff, elist, x1, stream);
    run_gat_layer(x1, 1024, 512,  Wl2, bl2, Wr2, br2, att2, b2,
                  xl, xr, sb, mEnc, den, srcA, dstA, eoff, elist, x2, stream);
    run_gat_layer(x2, 512,  256,  Wl3, bl3, Wr3, br3, att3, b3,
                  xl, xr, sb, mEnc, den, srcA, dstA, eoff, elist, x3, stream);

    // gate + pool + MLP
    k_gate<<<NN, 128, 0, stream>>>(x3, Wg0, bg0, Wg1, bg1, g);
    k_zero32<<<1, 64, 0, stream>>>((unsigned int*)gstart, 2 * NG);
    k_group_bounds<<<(NN + 255) / 256, 256, 0, stream>>>(batch, gstart, gend);
    k_pool<<<NG, 256, 0, stream>>>(x3, g, gstart, gend, hpool);
    k_mlp<<<1, 256, 0, stream>>>(hpool, Wm0, bm0, Wm1, bm1, Wm2, bm2,
                                 Wm3, bm3, Wm4, bm4, out);
}

// Round 2
// 1992.256 us; speedup vs baseline: 1.6568x; 1.6568x over previous
//
#include <hip/hip_runtime.h>
#include <math.h>

// Problem constants (from reference)
#define NN 5000
#define NE 50000
#define NEE 55000   // edges + self loops
#define NG 8
#define NH 4

typedef __attribute__((ext_vector_type(8))) _Float16 half8;
typedef __attribute__((ext_vector_type(4))) float floatx4;

// ---------------- utility device functions ----------------

__device__ inline float waveSum(float v) {
    #pragma unroll
    for (int o = 32; o > 0; o >>= 1) v += __shfl_xor(v, o, 64);
    return v;
}
__device__ inline float waveMax(float v) {
    #pragma unroll
    for (int o = 32; o > 0; o >>= 1) v = fmaxf(v, __shfl_xor(v, o, 64));
    return v;
}

// monotone float<->uint encoding for atomicMax on signed floats
__device__ inline unsigned int fenc(float f) {
    unsigned int u = __float_as_uint(f);
    return (u & 0x80000000u) ? ~u : (u | 0x80000000u);
}
__device__ inline float fdec(unsigned int u) {
    u = (u & 0x80000000u) ? (u & 0x7fffffffu) : ~u;
    return __uint_as_float(u);
}

// ---------------- fp32 -> fp16 split conversion ----------------

// elementwise: X (R*K fp32) -> A0,A1 fp16 planes (same layout)
__global__ void k_splitA(const float* __restrict__ X, _Float16* __restrict__ A0,
                         _Float16* __restrict__ A1, int n) {
    int i = blockIdx.x * 256 + threadIdx.x;
    if (i >= n) return;
    float v = X[i];
    _Float16 h0 = (_Float16)v;
    _Float16 h1 = (_Float16)(v - (float)h0);
    A0[i] = h0; A1[i] = h1;
}

// W (K x M fp32, row-major) -> B0,B1 fp16 planes TRANSPOSED to (M x K)
// LDS-tiled 32x32 transpose; K,M multiples of 32.
__global__ __launch_bounds__(256) void k_splitWT(const float* __restrict__ W,
        _Float16* __restrict__ B0, _Float16* __restrict__ B1, int K, int M)
{
    __shared__ float tile[32][33];
    int m0 = blockIdx.x * 32, k0 = blockIdx.y * 32;
    int tx = threadIdx.x & 31, ty = threadIdx.x >> 5;  // ty 0..7
    #pragma unroll
    for (int i = 0; i < 4; ++i)
        tile[ty + 8 * i][tx] = W[(size_t)(k0 + ty + 8 * i) * M + m0 + tx];
    __syncthreads();
    #pragma unroll
    for (int i = 0; i < 4; ++i) {
        int mm = ty + 8 * i, kk = tx;
        float v = tile[kk][mm];
        _Float16 h0 = (_Float16)v;
        _Float16 h1 = (_Float16)(v - (float)h0);
        size_t oi = (size_t)(m0 + mm) * K + kk + k0;
        B0[oi] = h0; B1[oi] = h1;
    }
}

// ---------------- MFMA split-fp16 GEMM ----------------
// C(Mrows x N) = A(Mrows x K) @ B(K x N) + bias, where
// A given as fp16 planes A0,A1 (Mrows x K); B as transposed planes B0,B1 (N x K).
// C ~= A0*B0 + A0*B1 + A1*B0  (a1*b1 term ~2^-24, dropped)
#define LDSPAD 40  // LDS row stride in halfs (32 data + 8 pad; 80B, 16B-aligned)

__global__ __launch_bounds__(256) void gemm_mfma_split(
    const _Float16* __restrict__ A0, const _Float16* __restrict__ A1,
    const _Float16* __restrict__ B0, const _Float16* __restrict__ B1,
    const float* __restrict__ bias, float* __restrict__ C,
    int Mrows, int K, int N)
{
    __shared__ _Float16 As0[128][LDSPAD];
    __shared__ _Float16 As1[128][LDSPAD];
    __shared__ _Float16 Bs0[128][LDSPAD];
    __shared__ _Float16 Bs1[128][LDSPAD];

    const int tid = threadIdx.x;
    const int wave = tid >> 6;
    const int lane = tid & 63;
    const int wm = (wave >> 1) * 64;   // wave row quadrant
    const int wn = (wave & 1) * 64;    // wave col quadrant
    const int lm = lane & 15;          // fragment 16-dim index
    const int kq = (lane >> 4) * 8;    // fragment k offset
    const int rowBase = blockIdx.y * 128;
    const int colBase = blockIdx.x * 128;

    floatx4 acc[4][4];
    #pragma unroll
    for (int i = 0; i < 4; ++i)
        #pragma unroll
        for (int j = 0; j < 4; ++j)
            acc[i][j] = (floatx4){0.f, 0.f, 0.f, 0.f};

    // staging plan: per plane, 512 16B-chunks; thread t takes chunks 2t,2t+1
    const int srow = tid >> 1;            // 0..127
    const int sko  = (tid & 1) * 16;      // 0 or 16 (two 8-half chunks)

    for (int k0 = 0; k0 < K; k0 += 32) {
        // ---- stage A planes (row-guarded) ----
        {
            int grow = rowBase + srow;
            float4 v0 = make_float4(0.f, 0.f, 0.f, 0.f), v1 = v0, v2 = v0, v3 = v0;
            if (grow < Mrows) {
                const float4* pa0 = (const float4*)(A0 + (size_t)grow * K + k0 + sko);
                const float4* pa1 = (const float4*)(A1 + (size_t)grow * K + k0 + sko);
                v0 = pa0[0]; v1 = pa0[1];
                v2 = pa1[0]; v3 = pa1[1];
            }
            *(float4*)&As0[srow][sko]     = v0;
            *(float4*)&As0[srow][sko + 8] = v1;
            *(float4*)&As1[srow][sko]     = v2;
            *(float4*)&As1[srow][sko + 8] = v3;
        }
        // ---- stage B planes (N multiple of 128, no guard) ----
        {
            const float4* pb0 = (const float4*)(B0 + (size_t)(colBase + srow) * K + k0 + sko);
            const float4* pb1 = (const float4*)(B1 + (size_t)(colBase + srow) * K + k0 + sko);
            float4 v0 = pb0[0], v1 = pb0[1], v2 = pb1[0], v3 = pb1[1];
            *(float4*)&Bs0[srow][sko]     = v0;
            *(float4*)&Bs0[srow][sko + 8] = v1;
            *(float4*)&Bs1[srow][sko]     = v2;
            *(float4*)&Bs1[srow][sko + 8] = v3;
        }
        __syncthreads();

        half8 a0[4], a1[4], b0[4], b1[4];
        #pragma unroll
        for (int i = 0; i < 4; ++i) {
            a0[i] = *(const half8*)&As0[wm + i * 16 + lm][kq];
            a1[i] = *(const half8*)&As1[wm + i * 16 + lm][kq];
            b0[i] = *(const half8*)&Bs0[wn + i * 16 + lm][kq];
            b1[i] = *(const half8*)&Bs1[wn + i * 16 + lm][kq];
        }
        #pragma unroll
        for (int i = 0; i < 4; ++i)
            #pragma unroll
            for (int j = 0; j < 4; ++j) {
                acc[i][j] = __builtin_amdgcn_mfma_f32_16x16x32_f16(a0[i], b0[j], acc[i][j], 0, 0, 0);
                acc[i][j] = __builtin_amdgcn_mfma_f32_16x16x32_f16(a1[i], b0[j], acc[i][j], 0, 0, 0);
                acc[i][j] = __builtin_amdgcn_mfma_f32_16x16x32_f16(a0[i], b1[j], acc[i][j], 0, 0, 0);
            }
        __syncthreads();
    }

    // epilogue: C/D layout col=lane&15, row=(lane>>4)*4+reg
    const int cq = (lane >> 4) * 4;
    #pragma unroll
    for (int j = 0; j < 4; ++j) {
        int col = colBase + wn + j * 16 + lm;
        float bv = bias[col];
        #pragma unroll
        for (int i = 0; i < 4; ++i) {
            #pragma unroll
            for (int r = 0; r < 4; ++r) {
                int grow = rowBase + wm + i * 16 + cq + r;
                if (grow < Mrows)
                    C[(size_t)grow * N + col] = acc[i][j][r] + bv;
            }
        }
    }
}

// ---------------- edge / graph kernels ----------------

__global__ void k_build_edges(const int* __restrict__ ei, int* __restrict__ src,
                              int* __restrict__ dst) {
    int i = blockIdx.x * 256 + threadIdx.x;
    if (i < NE) { src[i] = ei[i]; dst[i] = ei[NE + i]; }
    else if (i < NEE) { src[i] = i - NE; dst[i] = i - NE; }
}

__global__ void k_zero32(unsigned int* __restrict__ p, int n) {
    int i = blockIdx.x * 256 + threadIdx.x;
    if (i < n) p[i] = 0u;
}

__global__ void k_count(const int* __restrict__ dst, int* __restrict__ cnt) {
    int i = blockIdx.x * 256 + threadIdx.x;
    if (i < NEE) atomicAdd(&cnt[dst[i]], 1);
}

__global__ __launch_bounds__(256) void k_scan(const int* __restrict__ cnt,
                                              int* __restrict__ off, int* __restrict__ cur) {
    __shared__ int partial[256];
    __shared__ int ppre[257];
    int t = threadIdx.x;
    const int chunk = (NN + 255) / 256;
    int lo = t * chunk, hi = min(NN, (t + 1) * chunk);
    int s = 0;
    for (int i = lo; i < hi; ++i) s += cnt[i];
    partial[t] = s;
    __syncthreads();
    if (t == 0) {
        int acc = 0;
        for (int i = 0; i < 256; ++i) { ppre[i] = acc; acc += partial[i]; }
        ppre[256] = acc;
    }
    __syncthreads();
    int acc = ppre[t];
    for (int i = lo; i < hi; ++i) { off[i] = acc; cur[i] = acc; acc += cnt[i]; }
    if (t == 0) off[NN] = ppre[256];
}

__global__ void k_fill(const int* __restrict__ dst, int* __restrict__ cur,
                       int* __restrict__ elist) {
    int e = blockIdx.x * 256 + threadIdx.x;
    if (e < NEE) { int p = atomicAdd(&cur[dst[e]], 1); elist[p] = e; }
}

// per-edge attention scores
__global__ __launch_bounds__(256) void k_edge_score(
    const float* __restrict__ xl, const float* __restrict__ xr,
    const float* __restrict__ att, const int* __restrict__ src,
    const int* __restrict__ dst, float* __restrict__ s, int C)
{
    int e = blockIdx.x;
    int h = threadIdx.x >> 6;
    int lane = threadIdx.x & 63;
    int se = src[e], de = dst[e];
    const float* pl = xl + (size_t)se * (NH * C) + h * C;
    const float* pr = xr + (size_t)de * (NH * C) + h * C;
    const float* pa = att + h * C;
    float acc = 0.f;
    for (int c = lane; c < C; c += 64) {
        float v = pl[c] + pr[c];
        v = v > 0.f ? v : 0.2f * v;
        acc = fmaf(v, pa[c], acc);
    }
    acc = waveSum(acc);
    if (lane == 0) s[(size_t)e * NH + h] = acc;
}

__global__ void k_init_md(unsigned int* __restrict__ mEnc, float* __restrict__ den) {
    int i = blockIdx.x * 256 + threadIdx.x;
    if (i < NN * NH) { mEnc[i] = 0u; den[i] = 0.f; }
}

__global__ void k_seg_max(const float* __restrict__ s, const int* __restrict__ dst,
                          unsigned int* __restrict__ mEnc) {
    int i = blockIdx.x * 256 + threadIdx.x;
    if (i >= NEE * NH) return;
    int e = i >> 2, h = i & 3;
    atomicMax(&mEnc[dst[e] * NH + h], fenc(s[i]));
}

__global__ void k_exp_den(float* __restrict__ s, const int* __restrict__ dst,
                          const unsigned int* __restrict__ mEnc, float* __restrict__ den) {
    int i = blockIdx.x * 256 + threadIdx.x;
    if (i >= NEE * NH) return;
    int e = i >> 2, h = i & 3;
    float m = fdec(mEnc[dst[e] * NH + h]);
    float ex = expf(s[i] - m);
    s[i] = ex;
    atomicAdd(&den[dst[e] * NH + h], ex);
}

__global__ void k_alpha(float* __restrict__ s, const int* __restrict__ dst,
                        const float* __restrict__ den) {
    int i = blockIdx.x * 256 + threadIdx.x;
    if (i >= NEE * NH) return;
    int e = i >> 2, h = i & 3;
    s[i] = s[i] / (den[dst[e] * NH + h] + 1e-16f);
}

__global__ __launch_bounds__(256) void k_aggregate(
    const float* __restrict__ xl, const float* __restrict__ alpha,
    const int* __restrict__ eoff, const int* __restrict__ elist,
    const int* __restrict__ src, const float* __restrict__ bias,
    float* __restrict__ out, int C)
{
    int n = blockIdx.x;
    int start = eoff[n], end = eoff[n + 1];
    for (int c = threadIdx.x; c < C; c += 256) {
        float a0 = 0.f, a1 = 0.f, a2 = 0.f, a3 = 0.f;
        for (int j = start; j < end; ++j) {
            int e = elist[j];
            int sn = src[e];
            const float* pl = xl + (size_t)sn * NH * C;
            const float* pa = alpha + (size_t)e * NH;
            a0 = fmaf(pa[0], pl[c], a0);
            a1 = fmaf(pa[1], pl[C + c], a1);
            a2 = fmaf(pa[2], pl[2 * C + c], a2);
            a3 = fmaf(pa[3], pl[3 * C + c], a3);
        }
        float v = (a0 + a1 + a2 + a3) * 0.25f + bias[c];
        out[(size_t)n * C + c] = v > 0.f ? v : 0.f;
    }
}

// ---------------- gate + pool + MLP ----------------

__global__ __launch_bounds__(128) void k_gate(
    const float* __restrict__ x, const float* __restrict__ Wg0,
    const float* __restrict__ bg0, const float* __restrict__ Wg1,
    const float* __restrict__ bg1, float* __restrict__ g)
{
    int n = blockIdx.x;
    int t = threadIdx.x;
    __shared__ float xs[256];
    __shared__ float wsum[2];
    const float* xp = x + (size_t)n * 256;
    xs[t] = xp[t]; xs[t + 128] = xp[t + 128];
    __syncthreads();
    float acc = bg0[t];
    for (int k = 0; k < 256; ++k) acc = fmaf(xs[k], Wg0[k * 128 + t], acc);
    acc = acc > 0.f ? acc : 0.f;
    float prod = acc * Wg1[t];
    prod = waveSum(prod);
    if ((t & 63) == 0) wsum[t >> 6] = prod;
    __syncthreads();
    if (t == 0) g[n] = wsum[0] + wsum[1] + bg1[0];
}

__global__ void k_group_bounds(const int* __restrict__ batch, int* __restrict__ gstart,
                               int* __restrict__ gend) {
    int n = blockIdx.x * 256 + threadIdx.x;
    if (n >= NN) return;
    int b = batch[n];
    if (n == 0 || batch[n - 1] != b) gstart[b] = n;
    if (n == NN - 1 || batch[n + 1] != b) gend[b] = n + 1;
}

__global__ __launch_bounds__(256) void k_pool(
    const float* __restrict__ x, const float* __restrict__ g,
    const int* __restrict__ gstart, const int* __restrict__ gend,
    float* __restrict__ hpool)
{
    int gi = blockIdx.x;
    int t = threadIdx.x;
    int s0 = gstart[gi], e0 = gend[gi];
    __shared__ float red[4];
    float mx = -1e30f;
    for (int n = s0 + t; n < e0; n += 256) mx = fmaxf(mx, g[n]);
    float wm = waveMax(mx);
    if ((t & 63) == 0) red[t >> 6] = wm;
    __syncthreads();
    float m = fmaxf(fmaxf(red[0], red[1]), fmaxf(red[2], red[3]));
    __syncthreads();
    float sm = 0.f;
    for (int n = s0 + t; n < e0; n += 256) sm += expf(g[n] - m);
    sm = waveSum(sm);
    if ((t & 63) == 0) red[t >> 6] = sm;
    __syncthreads();
    float den = red[0] + red[1] + red[2] + red[3] + 1e-16f;
    float acc = 0.f;
    for (int n = s0; n < e0; ++n) {
        float w = expf(g[n] - m) / den;
        acc = fmaf(w, x[(size_t)n * 256 + t], acc);
    }
    hpool[gi * 256 + t] = acc;
}

__global__ __launch_bounds__(256) void k_mlp(
    const float* __restrict__ hpool,
    const float* __restrict__ Wm0, const float* __restrict__ bm0,
    const float* __restrict__ Wm1, const float* __restrict__ bm1,
    const float* __restrict__ Wm2, const float* __restrict__ bm2,
    const float* __restrict__ Wm3, const float* __restrict__ bm3,
    const float* __restrict__ Wm4, const float* __restrict__ bm4,
    float* __restrict__ out)
{
    __shared__ float bufA[8 * 256];
    __shared__ float bufB[8 * 128];
    int t = threadIdx.x;
    for (int i = t; i < 8 * 256; i += 256) bufA[i] = hpool[i];
    __syncthreads();
    for (int i = t; i < 8 * 128; i += 256) {
        int r = i >> 7, c = i & 127;
        float acc = bm0[c];
        for (int k = 0; k < 256; ++k) acc = fmaf(bufA[r * 256 + k], Wm0[k * 128 + c], acc);
        bufB[i] = fmaxf(acc, 0.f);
    }
    __syncthreads();
    for (int i = t; i < 8 * 64; i += 256) {
        int r = i >> 6, c = i & 63;
        float acc = bm1[c];
        for (int k = 0; k < 128; ++k) acc = fmaf(bufB[r * 128 + k], Wm1[k * 64 + c], acc);
        bufA[i] = fmaxf(acc, 0.f);
    }
    __syncthreads();
    for (int i = t; i < 8 * 32; i += 256) {
        int r = i >> 5, c = i & 31;
        float acc = bm2[c];
        for (int k = 0; k < 64; ++k) acc = fmaf(bufA[r * 64 + k], Wm2[k * 32 + c], acc);
        bufB[i] = fmaxf(acc, 0.f);
    }
    __syncthreads();
    for (int i = t; i < 8 * 16; i += 256) {
        int r = i >> 4, c = i & 15;
        float acc = bm3[c];
        for (int k = 0; k < 32; ++k) acc = fmaf(bufB[r * 32 + k], Wm3[k * 16 + c], acc);
        bufA[i] = fmaxf(acc, 0.f);
    }
    __syncthreads();
    if (t < 8) {
        float acc = bm4[0];
        for (int k = 0; k < 16; ++k) acc = fmaf(bufA[t * 16 + k], Wm4[k], acc);
        out[t] = acc;
    }
}

// ---------------- host orchestration ----------------

static void run_gat_layer(const float* xin, int K, int C,
                          const float* Wl, const float* bl,
                          const float* Wr, const float* br,
                          const float* att, const float* bias,
                          _Float16* a0p, _Float16* a1p,
                          _Float16* wb0, _Float16* wb1,
                          float* xl, float* xr, float* sb,
                          unsigned int* mEnc, float* den,
                          const int* srcA, const int* dstA,
                          const int* eoff, const int* elist,
                          float* xout, hipStream_t stream)
{
    int HC = NH * C;
    // split A into fp16 planes
    int nA = NN * K;
    k_splitA<<<(nA + 255) / 256, 256, 0, stream>>>(xin, a0p, a1p, nA);
    dim3 ggrid(HC / 128, (NN + 127) / 128);
    dim3 tgrid(HC / 32, K / 32);
    // Wl -> planes -> xl
    k_splitWT<<<tgrid, 256, 0, stream>>>(Wl, wb0, wb1, K, HC);
    gemm_mfma_split<<<ggrid, 256, 0, stream>>>(a0p, a1p, wb0, wb1, bl, xl, NN, K, HC);
    // Wr -> planes (reuse buffer) -> xr
    k_splitWT<<<tgrid, 256, 0, stream>>>(Wr, wb0, wb1, K, HC);
    gemm_mfma_split<<<ggrid, 256, 0, stream>>>(a0p, a1p, wb0, wb1, br, xr, NN, K, HC);

    k_edge_score<<<NEE, 256, 0, stream>>>(xl, xr, att, srcA, dstA, sb, C);
    k_init_md<<<(NN * NH + 255) / 256, 256, 0, stream>>>(mEnc, den);
    int eb = (NEE * NH + 255) / 256;
    k_seg_max<<<eb, 256, 0, stream>>>(sb, dstA, mEnc);
    k_exp_den<<<eb, 256, 0, stream>>>(sb, dstA, mEnc, den);
    k_alpha<<<eb, 256, 0, stream>>>(sb, dstA, den);
    k_aggregate<<<NN, 256, 0, stream>>>(xl, sb, eoff, elist, srcA, bias, xout, C);
}

extern "C" void kernel_launch(void* const* d_in, const int* in_sizes, int n_in,
                              void* d_out, int out_size, void* d_ws, size_t ws_size,
                              hipStream_t stream) {
    const float* x      = (const float*)d_in[0];
    const int* ei       = (const int*)d_in[1];
    const int* batch    = (const int*)d_in[2];
    const float* Wl1 = (const float*)d_in[3];  const float* bl1 = (const float*)d_in[4];
    const float* Wr1 = (const float*)d_in[5];  const float* br1 = (const float*)d_in[6];
    const float* att1= (const float*)d_in[7];  const float* b1  = (const float*)d_in[8];
    const float* Wl2 = (const float*)d_in[9];  const float* bl2 = (const float*)d_in[10];
    const float* Wr2 = (const float*)d_in[11]; const float* br2 = (const float*)d_in[12];
    const float* att2= (const float*)d_in[13]; const float* b2  = (const float*)d_in[14];
    const float* Wl3 = (const float*)d_in[15]; const float* bl3 = (const float*)d_in[16];
    const float* Wr3 = (const float*)d_in[17]; const float* br3 = (const float*)d_in[18];
    const float* att3= (const float*)d_in[19]; const float* b3  = (const float*)d_in[20];
    const float* Wm0 = (const float*)d_in[21]; const float* bm0 = (const float*)d_in[22];
    const float* Wm1 = (const float*)d_in[23]; const float* bm1 = (const float*)d_in[24];
    const float* Wm2 = (const float*)d_in[25]; const float* bm2 = (const float*)d_in[26];
    const float* Wm3 = (const float*)d_in[27]; const float* bm3 = (const float*)d_in[28];
    const float* Wm4 = (const float*)d_in[29]; const float* bm4 = (const float*)d_in[30];
    const float* Wg0 = (const float*)d_in[31]; const float* bg0 = (const float*)d_in[32];
    const float* Wg1 = (const float*)d_in[33]; const float* bg1 = (const float*)d_in[34];
    float* out = (float*)d_out;

    // workspace carve (float units = 4B)
    float* ws = (float*)d_ws;
    size_t o = 0;
    float* xl    = ws + o; o += (size_t)NN * 4096;
    float* xr    = ws + o; o += (size_t)NN * 4096;
    float* x1    = ws + o; o += (size_t)NN * 1024;
    float* x2    = ws + o; o += (size_t)NN * 512;
    float* x3    = ws + o; o += (size_t)NN * 256;
    float* sb    = ws + o; o += (size_t)NEE * NH;
    unsigned int* mEnc = (unsigned int*)(ws + o); o += NN * NH;
    float* den   = ws + o; o += NN * NH;
    int* srcA    = (int*)(ws + o); o += NEE;
    int* dstA    = (int*)(ws + o); o += NEE;
    int* cnt     = (int*)(ws + o); o += NN;
    int* eoff    = (int*)(ws + o); o += NN + 1;
    int* cur     = (int*)(ws + o); o += NN;
    int* elist   = (int*)(ws + o); o += NEE;
    float* g     = ws + o; o += NN;
    int* gstart  = (int*)(ws + o); o += NG;
    int* gend    = (int*)(ws + o); o += NG;
    float* hpool = ws + o; o += NG * 256;
    // fp16 plane buffers (sized for layer 1, reused across layers)
    _Float16* a0p = (_Float16*)(ws + o); o += (size_t)NN * 1536 / 2;      // 5000x1536 halfs
    _Float16* a1p = (_Float16*)(ws + o); o += (size_t)NN * 1536 / 2;
    _Float16* wb0 = (_Float16*)(ws + o); o += (size_t)1536 * 4096 / 2;    // 1536x4096 halfs
    _Float16* wb1 = (_Float16*)(ws + o); o += (size_t)1536 * 4096 / 2;

    // build CSR by dst
    int ebB = (NEE + 255) / 256;
    k_build_edges<<<ebB, 256, 0, stream>>>(ei, srcA, dstA);
    k_zero32<<<(NN + 255) / 256, 256, 0, stream>>>((unsigned int*)cnt, NN);
    k_count<<<ebB, 256, 0, stream>>>(dstA, cnt);
    k_scan<<<1, 256, 0, stream>>>(cnt, eoff, cur);
    k_fill<<<ebB, 256, 0, stream>>>(dstA, cur, elist);

    // three GATv2 layers
    run_gat_layer(x,  1536, 1024, Wl1, bl1, Wr1, br1, att1, b1,
                  a0p, a1p, wb0, wb1,
                  xl, xr, sb, mEnc, den, srcA, dstA, eoff, elist, x1, stream);
    run_gat_layer(x1, 1024, 512,  Wl2, bl2, Wr2, br2, att2, b2,
                  a0p, a1p, wb0, wb1,
                  xl, xr, sb, mEnc, den, srcA, dstA, eoff, elist, x2, stream);
    run_gat_layer(x2, 512,  256,  Wl3, bl3, Wr3, br3, att3, b3,
                  a0p, a1p, wb0, wb1,
                  xl, xr, sb, mEnc, den, srcA, dstA, eoff, elist, x3, stream);

    // gate + pool + MLP
    k_gate<<<NN, 128, 0, stream>>>(x3, Wg0, bg0, Wg1, bg1, g);
    k_zero32<<<1, 64, 0, stream>>>((unsigned int*)gstart, 2 * NG);
    k_group_bounds<<<(NN + 255) / 256, 256, 0, stream>>>(batch, gstart, gend);
    k_pool<<<NG, 256, 0, stream>>>(x3, g, gstart, gend, hpool);
    k_mlp<<<1, 256, 0, stream>>>(hpool, Wm0, bm0, Wm1, bm1, Wm2, bm2,
                                 Wm3, bm3, Wm4, bm4, out);
}

// Round 3
// 1521.281 us; speedup vs baseline: 2.1698x; 1.3096x over previous
//
#include <hip/hip_runtime.h>
#include <math.h>

// Problem constants (from reference)
#define NN 5000
#define NE 50000
#define NEE 55000   // edges + self loops
#define NG 8
#define NH 4

typedef __attribute__((ext_vector_type(8))) _Float16 half8;
typedef __attribute__((ext_vector_type(4))) float floatx4;

// ---------------- utility device functions ----------------

__device__ inline float waveSum(float v) {
    #pragma unroll
    for (int o = 32; o > 0; o >>= 1) v += __shfl_xor(v, o, 64);
    return v;
}
__device__ inline float waveMax(float v) {
    #pragma unroll
    for (int o = 32; o > 0; o >>= 1) v = fmaxf(v, __shfl_xor(v, o, 64));
    return v;
}

// ---------------- fp32 -> fp16 split conversion ----------------

__global__ void k_splitA(const float* __restrict__ X, _Float16* __restrict__ A0,
                         _Float16* __restrict__ A1, int n) {
    int i = blockIdx.x * 256 + threadIdx.x;
    if (i >= n) return;
    float v = X[i];
    _Float16 h0 = (_Float16)v;
    _Float16 h1 = (_Float16)(v - (float)h0);
    A0[i] = h0; A1[i] = h1;
}

// W (K x M fp32) -> B0,B1 fp16 planes TRANSPOSED to (M x K)
__global__ __launch_bounds__(256) void k_splitWT(const float* __restrict__ W,
        _Float16* __restrict__ B0, _Float16* __restrict__ B1, int K, int M)
{
    __shared__ float tile[32][33];
    int m0 = blockIdx.x * 32, k0 = blockIdx.y * 32;
    int tx = threadIdx.x & 31, ty = threadIdx.x >> 5;
    #pragma unroll
    for (int i = 0; i < 4; ++i)
        tile[ty + 8 * i][tx] = W[(size_t)(k0 + ty + 8 * i) * M + m0 + tx];
    __syncthreads();
    #pragma unroll
    for (int i = 0; i < 4; ++i) {
        int mm = ty + 8 * i, kk = tx;
        float v = tile[kk][mm];
        _Float16 h0 = (_Float16)v;
        _Float16 h1 = (_Float16)(v - (float)h0);
        size_t oi = (size_t)(m0 + mm) * K + kk + k0;
        B0[oi] = h0; B1[oi] = h1;
    }
}

// ---------------- MFMA split-fp16 GEMM ----------------
// C ~= A0*B0 + A0*B1 + A1*B0  (a1*b1 term ~2^-24, dropped)
#define LDSPAD 40

__global__ __launch_bounds__(256) void gemm_mfma_split(
    const _Float16* __restrict__ A0, const _Float16* __restrict__ A1,
    const _Float16* __restrict__ B0, const _Float16* __restrict__ B1,
    const float* __restrict__ bias, float* __restrict__ C,
    int Mrows, int K, int N)
{
    __shared__ _Float16 As0[128][LDSPAD];
    __shared__ _Float16 As1[128][LDSPAD];
    __shared__ _Float16 Bs0[128][LDSPAD];
    __shared__ _Float16 Bs1[128][LDSPAD];

    const int tid = threadIdx.x;
    const int wave = tid >> 6;
    const int lane = tid & 63;
    const int wm = (wave >> 1) * 64;
    const int wn = (wave & 1) * 64;
    const int lm = lane & 15;
    const int kq = (lane >> 4) * 8;
    const int rowBase = blockIdx.y * 128;
    const int colBase = blockIdx.x * 128;

    floatx4 acc[4][4];
    #pragma unroll
    for (int i = 0; i < 4; ++i)
        #pragma unroll
        for (int j = 0; j < 4; ++j)
            acc[i][j] = (floatx4){0.f, 0.f, 0.f, 0.f};

    const int srow = tid >> 1;
    const int sko  = (tid & 1) * 16;

    for (int k0 = 0; k0 < K; k0 += 32) {
        {
            int grow = rowBase + srow;
            float4 v0 = make_float4(0.f, 0.f, 0.f, 0.f), v1 = v0, v2 = v0, v3 = v0;
            if (grow < Mrows) {
                const float4* pa0 = (const float4*)(A0 + (size_t)grow * K + k0 + sko);
                const float4* pa1 = (const float4*)(A1 + (size_t)grow * K + k0 + sko);
                v0 = pa0[0]; v1 = pa0[1];
                v2 = pa1[0]; v3 = pa1[1];
            }
            *(float4*)&As0[srow][sko]     = v0;
            *(float4*)&As0[srow][sko + 8] = v1;
            *(float4*)&As1[srow][sko]     = v2;
            *(float4*)&As1[srow][sko + 8] = v3;
        }
        {
            const float4* pb0 = (const float4*)(B0 + (size_t)(colBase + srow) * K + k0 + sko);
            const float4* pb1 = (const float4*)(B1 + (size_t)(colBase + srow) * K + k0 + sko);
            float4 v0 = pb0[0], v1 = pb0[1], v2 = pb1[0], v3 = pb1[1];
            *(float4*)&Bs0[srow][sko]     = v0;
            *(float4*)&Bs0[srow][sko + 8] = v1;
            *(float4*)&Bs1[srow][sko]     = v2;
            *(float4*)&Bs1[srow][sko + 8] = v3;
        }
        __syncthreads();

        half8 a0[4], a1[4], b0[4], b1[4];
        #pragma unroll
        for (int i = 0; i < 4; ++i) {
            a0[i] = *(const half8*)&As0[wm + i * 16 + lm][kq];
            a1[i] = *(const half8*)&As1[wm + i * 16 + lm][kq];
            b0[i] = *(const half8*)&Bs0[wn + i * 16 + lm][kq];
            b1[i] = *(const half8*)&Bs1[wn + i * 16 + lm][kq];
        }
        #pragma unroll
        for (int i = 0; i < 4; ++i)
            #pragma unroll
            for (int j = 0; j < 4; ++j) {
                acc[i][j] = __builtin_amdgcn_mfma_f32_16x16x32_f16(a0[i], b0[j], acc[i][j], 0, 0, 0);
                acc[i][j] = __builtin_amdgcn_mfma_f32_16x16x32_f16(a1[i], b0[j], acc[i][j], 0, 0, 0);
                acc[i][j] = __builtin_amdgcn_mfma_f32_16x16x32_f16(a0[i], b1[j], acc[i][j], 0, 0, 0);
            }
        __syncthreads();
    }

    const int cq = (lane >> 4) * 4;
    #pragma unroll
    for (int j = 0; j < 4; ++j) {
        int col = colBase + wn + j * 16 + lm;
        float bv = bias[col];
        #pragma unroll
        for (int i = 0; i < 4; ++i) {
            #pragma unroll
            for (int r = 0; r < 4; ++r) {
                int grow = rowBase + wm + i * 16 + cq + r;
                if (grow < Mrows)
                    C[(size_t)grow * N + col] = acc[i][j][r] + bv;
            }
        }
    }
}

// ---------------- CSR build ----------------

__global__ void k_build_edges(const int* __restrict__ ei, int* __restrict__ src,
                              int* __restrict__ dst) {
    int i = blockIdx.x * 256 + threadIdx.x;
    if (i < NE) { src[i] = ei[i]; dst[i] = ei[NE + i]; }
    else if (i < NEE) { src[i] = i - NE; dst[i] = i - NE; }
}

__global__ void k_zero32(unsigned int* __restrict__ p, int n) {
    int i = blockIdx.x * 256 + threadIdx.x;
    if (i < n) p[i] = 0u;
}

__global__ void k_count(const int* __restrict__ dst, int* __restrict__ cnt) {
    int i = blockIdx.x * 256 + threadIdx.x;
    if (i < NEE) atomicAdd(&cnt[dst[i]], 1);
}

__global__ __launch_bounds__(256) void k_scan(const int* __restrict__ cnt,
                                              int* __restrict__ off, int* __restrict__ cur) {
    __shared__ int partial[256];
    __shared__ int ppre[257];
    int t = threadIdx.x;
    const int chunk = (NN + 255) / 256;
    int lo = t * chunk, hi = min(NN, (t + 1) * chunk);
    int s = 0;
    for (int i = lo; i < hi; ++i) s += cnt[i];
    partial[t] = s;
    __syncthreads();
    if (t == 0) {
        int acc = 0;
        for (int i = 0; i < 256; ++i) { ppre[i] = acc; acc += partial[i]; }
        ppre[256] = acc;
    }
    __syncthreads();
    int acc = ppre[t];
    for (int i = lo; i < hi; ++i) { off[i] = acc; cur[i] = acc; acc += cnt[i]; }
    if (t == 0) off[NN] = ppre[256];
}

// stores SRC node id per CSR slot (not edge id) — fused kernel needs only src
__global__ void k_fill(const int* __restrict__ src, const int* __restrict__ dst,
                       int* __restrict__ cur, int* __restrict__ slist) {
    int e = blockIdx.x * 256 + threadIdx.x;
    if (e < NEE) { int p = atomicAdd(&cur[dst[e]], 1); slist[p] = src[e]; }
}

// ---------------- fused GATv2 edge pipeline ----------------
// Block per dst node; wave w owns head w. Online softmax, all state in regs.
// out[n,c] = relu( mean_h (sum_e ex*xl)/(den+eps) + bias[c] )
template<int C>
__global__ __launch_bounds__(256) void k_gat_fused(
    const float* __restrict__ xl, const float* __restrict__ xr,
    const float* __restrict__ att, const int* __restrict__ eoff,
    const int* __restrict__ slist, const float* __restrict__ bias,
    float* __restrict__ out)
{
    constexpr int NQ = C / 256;          // float4 chunks per lane: 4/2/1
    __shared__ float red[NH * C];        // epilogue head-mean buffer
    const int n = blockIdx.x;
    const int h = threadIdx.x >> 6;
    const int lane = threadIdx.x & 63;

    float4 xr_reg[NQ], att_reg[NQ], acc[NQ];
    {
        const float* xrow = xr + (size_t)n * (NH * C) + h * C;
        const float* ah   = att + h * C;
        #pragma unroll
        for (int q = 0; q < NQ; ++q) {
            int off = q * 256 + lane * 4;
            xr_reg[q]  = *(const float4*)(xrow + off);
            att_reg[q] = *(const float4*)(ah + off);
            acc[q] = make_float4(0.f, 0.f, 0.f, 0.f);
        }
    }
    float m = -INFINITY, den = 0.f;
    const int start = eoff[n], end = eoff[n + 1];

    for (int j = start; j < end; ++j) {
        int s = slist[j];
        const float* xlr = xl + (size_t)s * (NH * C) + h * C;
        float4 xv[NQ];
        float ps = 0.f;
        #pragma unroll
        for (int q = 0; q < NQ; ++q) {
            xv[q] = *(const float4*)(xlr + q * 256 + lane * 4);
            float vx = xv[q].x + xr_reg[q].x;
            float vy = xv[q].y + xr_reg[q].y;
            float vz = xv[q].z + xr_reg[q].z;
            float vw = xv[q].w + xr_reg[q].w;
            vx = vx > 0.f ? vx : 0.2f * vx;
            vy = vy > 0.f ? vy : 0.2f * vy;
            vz = vz > 0.f ? vz : 0.2f * vz;
            vw = vw > 0.f ? vw : 0.2f * vw;
            ps = fmaf(vx, att_reg[q].x, ps);
            ps = fmaf(vy, att_reg[q].y, ps);
            ps = fmaf(vz, att_reg[q].z, ps);
            ps = fmaf(vw, att_reg[q].w, ps);
        }
        ps = waveSum(ps);
        float m_new = fmaxf(m, ps);
        float scale = expf(m - m_new);
        float ex = expf(ps - m_new);
        den = den * scale + ex;
        m = m_new;
        #pragma unroll
        for (int q = 0; q < NQ; ++q) {
            acc[q].x = fmaf(ex, xv[q].x, acc[q].x * scale);
            acc[q].y = fmaf(ex, xv[q].y, acc[q].y * scale);
            acc[q].z = fmaf(ex, xv[q].z, acc[q].z * scale);
            acc[q].w = fmaf(ex, xv[q].w, acc[q].w * scale);
        }
    }

    // normalize, write per-head result to LDS
    float inv = 1.f / (den + 1e-16f);
    #pragma unroll
    for (int q = 0; q < NQ; ++q) {
        int off = q * 256 + lane * 4;
        float4 r;
        r.x = acc[q].x * inv; r.y = acc[q].y * inv;
        r.z = acc[q].z * inv; r.w = acc[q].w * inv;
        *(float4*)&red[h * C + off] = r;
    }
    __syncthreads();

    // mean over heads + bias + relu
    int t = threadIdx.x;
    for (int c4 = t; c4 < C / 4; c4 += 256) {
        int c = c4 * 4;
        float4 r0 = *(const float4*)&red[0 * C + c];
        float4 r1 = *(const float4*)&red[1 * C + c];
        float4 r2 = *(const float4*)&red[2 * C + c];
        float4 r3 = *(const float4*)&red[3 * C + c];
        float4 bv = *(const float4*)(bias + c);
        float4 o;
        o.x = fmaxf((r0.x + r1.x + r2.x + r3.x) * 0.25f + bv.x, 0.f);
        o.y = fmaxf((r0.y + r1.y + r2.y + r3.y) * 0.25f + bv.y, 0.f);
        o.z = fmaxf((r0.z + r1.z + r2.z + r3.z) * 0.25f + bv.z, 0.f);
        o.w = fmaxf((r0.w + r1.w + r2.w + r3.w) * 0.25f + bv.w, 0.f);
        *(float4*)(out + (size_t)n * C + c) = o;
    }
}

// ---------------- gate + pool + MLP ----------------

__global__ __launch_bounds__(128) void k_gate(
    const float* __restrict__ x, const float* __restrict__ Wg0,
    const float* __restrict__ bg0, const float* __restrict__ Wg1,
    const float* __restrict__ bg1, float* __restrict__ g)
{
    int n = blockIdx.x;
    int t = threadIdx.x;
    __shared__ float xs[256];
    __shared__ float wsum[2];
    const float* xp = x + (size_t)n * 256;
    xs[t] = xp[t]; xs[t + 128] = xp[t + 128];
    __syncthreads();
    float acc = bg0[t];
    for (int k = 0; k < 256; ++k) acc = fmaf(xs[k], Wg0[k * 128 + t], acc);
    acc = acc > 0.f ? acc : 0.f;
    float prod = acc * Wg1[t];
    prod = waveSum(prod);
    if ((t & 63) == 0) wsum[t >> 6] = prod;
    __syncthreads();
    if (t == 0) g[n] = wsum[0] + wsum[1] + bg1[0];
}

__global__ void k_group_bounds(const int* __restrict__ batch, int* __restrict__ gstart,
                               int* __restrict__ gend) {
    int n = blockIdx.x * 256 + threadIdx.x;
    if (n >= NN) return;
    int b = batch[n];
    if (n == 0 || batch[n - 1] != b) gstart[b] = n;
    if (n == NN - 1 || batch[n + 1] != b) gend[b] = n + 1;
}

__global__ __launch_bounds__(256) void k_pool(
    const float* __restrict__ x, const float* __restrict__ g,
    const int* __restrict__ gstart, const int* __restrict__ gend,
    float* __restrict__ hpool)
{
    int gi = blockIdx.x;
    int t = threadIdx.x;
    int s0 = gstart[gi], e0 = gend[gi];
    __shared__ float red[4];
    float mx = -1e30f;
    for (int n = s0 + t; n < e0; n += 256) mx = fmaxf(mx, g[n]);
    float wm = waveMax(mx);
    if ((t & 63) == 0) red[t >> 6] = wm;
    __syncthreads();
    float m = fmaxf(fmaxf(red[0], red[1]), fmaxf(red[2], red[3]));
    __syncthreads();
    float sm = 0.f;
    for (int n = s0 + t; n < e0; n += 256) sm += expf(g[n] - m);
    sm = waveSum(sm);
    if ((t & 63) == 0) red[t >> 6] = sm;
    __syncthreads();
    float den = red[0] + red[1] + red[2] + red[3] + 1e-16f;
    float acc = 0.f;
    for (int n = s0; n < e0; ++n) {
        float w = expf(g[n] - m) / den;
        acc = fmaf(w, x[(size_t)n * 256 + t], acc);
    }
    hpool[gi * 256 + t] = acc;
}

__global__ __launch_bounds__(256) void k_mlp(
    const float* __restrict__ hpool,
    const float* __restrict__ Wm0, const float* __restrict__ bm0,
    const float* __restrict__ Wm1, const float* __restrict__ bm1,
    const float* __restrict__ Wm2, const float* __restrict__ bm2,
    const float* __restrict__ Wm3, const float* __restrict__ bm3,
    const float* __restrict__ Wm4, const float* __restrict__ bm4,
    float* __restrict__ out)
{
    __shared__ float bufA[8 * 256];
    __shared__ float bufB[8 * 128];
    int t = threadIdx.x;
    for (int i = t; i < 8 * 256; i += 256) bufA[i] = hpool[i];
    __syncthreads();
    for (int i = t; i < 8 * 128; i += 256) {
        int r = i >> 7, c = i & 127;
        float acc = bm0[c];
        for (int k = 0; k < 256; ++k) acc = fmaf(bufA[r * 256 + k], Wm0[k * 128 + c], acc);
        bufB[i] = fmaxf(acc, 0.f);
    }
    __syncthreads();
    for (int i = t; i < 8 * 64; i += 256) {
        int r = i >> 6, c = i & 63;
        float acc = bm1[c];
        for (int k = 0; k < 128; ++k) acc = fmaf(bufB[r * 128 + k], Wm1[k * 64 + c], acc);
        bufA[i] = fmaxf(acc, 0.f);
    }
    __syncthreads();
    for (int i = t; i < 8 * 32; i += 256) {
        int r = i >> 5, c = i & 31;
        float acc = bm2[c];
        for (int k = 0; k < 64; ++k) acc = fmaf(bufA[r * 64 + k], Wm2[k * 32 + c], acc);
        bufB[i] = fmaxf(acc, 0.f);
    }
    __syncthreads();
    for (int i = t; i < 8 * 16; i += 256) {
        int r = i >> 4, c = i & 15;
        float acc = bm3[c];
        for (int k = 0; k < 32; ++k) acc = fmaf(bufB[r * 32 + k], Wm3[k * 16 + c], acc);
        bufA[i] = fmaxf(acc, 0.f);
    }
    __syncthreads();
    if (t < 8) {
        float acc = bm4[0];
        for (int k = 0; k < 16; ++k) acc = fmaf(bufA[t * 16 + k], Wm4[k], acc);
        out[t] = acc;
    }
}

// ---------------- host orchestration ----------------

static void run_gat_layer(const float* xin, int K, int C,
                          const float* Wl, const float* bl,
                          const float* Wr, const float* br,
                          const float* att, const float* bias,
                          _Float16* a0p, _Float16* a1p,
                          _Float16* wb0, _Float16* wb1,
                          float* xl, float* xr,
                          const int* eoff, const int* slist,
                          float* xout, hipStream_t stream)
{
    int HC = NH * C;
    int nA = NN * K;
    k_splitA<<<(nA + 255) / 256, 256, 0, stream>>>(xin, a0p, a1p, nA);
    dim3 ggrid(HC / 128, (NN + 127) / 128);
    dim3 tgrid(HC / 32, K / 32);
    k_splitWT<<<tgrid, 256, 0, stream>>>(Wl, wb0, wb1, K, HC);
    gemm_mfma_split<<<ggrid, 256, 0, stream>>>(a0p, a1p, wb0, wb1, bl, xl, NN, K, HC);
    k_splitWT<<<tgrid, 256, 0, stream>>>(Wr, wb0, wb1, K, HC);
    gemm_mfma_split<<<ggrid, 256, 0, stream>>>(a0p, a1p, wb0, wb1, br, xr, NN, K, HC);

    if (C == 1024)
        k_gat_fused<1024><<<NN, 256, 0, stream>>>(xl, xr, att, eoff, slist, bias, xout);
    else if (C == 512)
        k_gat_fused<512><<<NN, 256, 0, stream>>>(xl, xr, att, eoff, slist, bias, xout);
    else
        k_gat_fused<256><<<NN, 256, 0, stream>>>(xl, xr, att, eoff, slist, bias, xout);
}

extern "C" void kernel_launch(void* const* d_in, const int* in_sizes, int n_in,
                              void* d_out, int out_size, void* d_ws, size_t ws_size,
                              hipStream_t stream) {
    const float* x      = (const float*)d_in[0];
    const int* ei       = (const int*)d_in[1];
    const int* batch    = (const int*)d_in[2];
    const float* Wl1 = (const float*)d_in[3];  const float* bl1 = (const float*)d_in[4];
    const float* Wr1 = (const float*)d_in[5];  const float* br1 = (const float*)d_in[6];
    const float* att1= (const float*)d_in[7];  const float* b1  = (const float*)d_in[8];
    const float* Wl2 = (const float*)d_in[9];  const float* bl2 = (const float*)d_in[10];
    const float* Wr2 = (const float*)d_in[11]; const float* br2 = (const float*)d_in[12];
    const float* att2= (const float*)d_in[13]; const float* b2  = (const float*)d_in[14];
    const float* Wl3 = (const float*)d_in[15]; const float* bl3 = (const float*)d_in[16];
    const float* Wr3 = (const float*)d_in[17]; const float* br3 = (const float*)d_in[18];
    const float* att3= (const float*)d_in[19]; const float* b3  = (const float*)d_in[20];
    const float* Wm0 = (const float*)d_in[21]; const float* bm0 = (const float*)d_in[22];
    const float* Wm1 = (const float*)d_in[23]; const float* bm1 = (const float*)d_in[24];
    const float* Wm2 = (const float*)d_in[25]; const float* bm2 = (const float*)d_in[26];
    const float* Wm3 = (const float*)d_in[27]; const float* bm3 = (const float*)d_in[28];
    const float* Wm4 = (const float*)d_in[29]; const float* bm4 = (const float*)d_in[30];
    const float* Wg0 = (const float*)d_in[31]; const float* bg0 = (const float*)d_in[32];
    const float* Wg1 = (const float*)d_in[33]; const float* bg1 = (const float*)d_in[34];
    float* out = (float*)d_out;

    // workspace carve (float units = 4B)
    float* ws = (float*)d_ws;
    size_t o = 0;
    float* xl    = ws + o; o += (size_t)NN * 4096;
    float* xr    = ws + o; o += (size_t)NN * 4096;
    float* x1    = ws + o; o += (size_t)NN * 1024;
    float* x2    = ws + o; o += (size_t)NN * 512;
    float* x3    = ws + o; o += (size_t)NN * 256;
    int* srcA    = (int*)(ws + o); o += NEE;
    int* dstA    = (int*)(ws + o); o += NEE;
    int* cnt     = (int*)(ws + o); o += NN;
    int* eoff    = (int*)(ws + o); o += NN + 1;
    int* cur     = (int*)(ws + o); o += NN;
    int* slist   = (int*)(ws + o); o += NEE;
    float* g     = ws + o; o += NN;
    int* gstart  = (int*)(ws + o); o += NG;
    int* gend    = (int*)(ws + o); o += NG;
    float* hpool = ws + o; o += NG * 256;
    _Float16* a0p = (_Float16*)(ws + o); o += (size_t)NN * 1536 / 2;
    _Float16* a1p = (_Float16*)(ws + o); o += (size_t)NN * 1536 / 2;
    _Float16* wb0 = (_Float16*)(ws + o); o += (size_t)1536 * 4096 / 2;
    _Float16* wb1 = (_Float16*)(ws + o); o += (size_t)1536 * 4096 / 2;

    // build CSR by dst (slist holds src node ids)
    int ebB = (NEE + 255) / 256;
    k_build_edges<<<ebB, 256, 0, stream>>>(ei, srcA, dstA);
    k_zero32<<<(NN + 255) / 256, 256, 0, stream>>>((unsigned int*)cnt, NN);
    k_count<<<ebB, 256, 0, stream>>>(dstA, cnt);
    k_scan<<<1, 256, 0, stream>>>(cnt, eoff, cur);
    k_fill<<<ebB, 256, 0, stream>>>(srcA, dstA, cur, slist);

    // three GATv2 layers
    run_gat_layer(x,  1536, 1024, Wl1, bl1, Wr1, br1, att1, b1,
                  a0p, a1p, wb0, wb1, xl, xr, eoff, slist, x1, stream);
    run_gat_layer(x1, 1024, 512,  Wl2, bl2, Wr2, br2, att2, b2,
                  a0p, a1p, wb0, wb1, xl, xr, eoff, slist, x2, stream);
    run_gat_layer(x2, 512,  256,  Wl3, bl3, Wr3, br3, att3, b3,
                  a0p, a1p, wb0, wb1, xl, xr, eoff, slist, x3, stream);

    // gate + pool + MLP
    k_gate<<<NN, 128, 0, stream>>>(x3, Wg0, bg0, Wg1, bg1, g);
    k_zero32<<<1, 64, 0, stream>>>((unsigned int*)gstart, 2 * NG);
    k_group_bounds<<<(NN + 255) / 256, 256, 0, stream>>>(batch, gstart, gend);
    k_pool<<<NG, 256, 0, stream>>>(x3, g, gstart, gend, hpool);
    k_mlp<<<1, 256, 0, stream>>>(hpool, Wm0, bm0, Wm1, bm1, Wm2, bm2,
                                 Wm3, bm3, Wm4, bm4, out);
}

// Round 4
// 1157.666 us; speedup vs baseline: 2.8513x; 1.3141x over previous
//
#include <hip/hip_runtime.h>
#include <math.h>

// Problem constants (from reference)
#define NN 5000
#define NE 50000
#define NEE 55000   // edges + self loops
#define NG 8
#define NH 4

typedef __attribute__((ext_vector_type(8))) _Float16 half8;
typedef __attribute__((ext_vector_type(4))) float floatx4;

// ---------------- utility device functions ----------------

__device__ inline float waveSum(float v) {
    #pragma unroll
    for (int o = 32; o > 0; o >>= 1) v += __shfl_xor(v, o, 64);
    return v;
}
__device__ inline float waveMax(float v) {
    #pragma unroll
    for (int o = 32; o > 0; o >>= 1) v = fmaxf(v, __shfl_xor(v, o, 64));
    return v;
}

// ---------------- fp32 -> fp16 conversion ----------------

__global__ void k_cvtA(const float* __restrict__ X, _Float16* __restrict__ A0, int n) {
    int i = blockIdx.x * 256 + threadIdx.x;
    if (i >= n) return;
    A0[i] = (_Float16)X[i];
}

// W (K x M fp32) -> B0 fp16 TRANSPOSED to (M x K)
__global__ __launch_bounds__(256) void k_cvtWT(const float* __restrict__ W,
        _Float16* __restrict__ B0, int K, int M)
{
    __shared__ float tile[32][33];
    int m0 = blockIdx.x * 32, k0 = blockIdx.y * 32;
    int tx = threadIdx.x & 31, ty = threadIdx.x >> 5;
    #pragma unroll
    for (int i = 0; i < 4; ++i)
        tile[ty + 8 * i][tx] = W[(size_t)(k0 + ty + 8 * i) * M + m0 + tx];
    __syncthreads();
    #pragma unroll
    for (int i = 0; i < 4; ++i) {
        int mm = ty + 8 * i, kk = tx;
        B0[(size_t)(m0 + mm) * K + kk + k0] = (_Float16)tile[kk][mm];
    }
}

// ---------------- MFMA fp16 GEMM (single product) ----------------
// C(Mrows x N) = A(Mrows x K) @ B(K x N) + bias; A fp16 (Mrows x K),
// B fp16 transposed (N x K). Single fp16 product: rel err ~2^-11.
#define LDSPAD 40

__global__ __launch_bounds__(256) void gemm_mfma_f16(
    const _Float16* __restrict__ A0, const _Float16* __restrict__ B0,
    const float* __restrict__ bias, float* __restrict__ C,
    int Mrows, int K, int N)
{
    __shared__ _Float16 As0[128][LDSPAD];
    __shared__ _Float16 Bs0[128][LDSPAD];

    const int tid = threadIdx.x;
    const int wave = tid >> 6;
    const int lane = tid & 63;
    const int wm = (wave >> 1) * 64;
    const int wn = (wave & 1) * 64;
    const int lm = lane & 15;
    const int kq = (lane >> 4) * 8;
    const int rowBase = blockIdx.y * 128;
    const int colBase = blockIdx.x * 128;

    floatx4 acc[4][4];
    #pragma unroll
    for (int i = 0; i < 4; ++i)
        #pragma unroll
        for (int j = 0; j < 4; ++j)
            acc[i][j] = (floatx4){0.f, 0.f, 0.f, 0.f};

    const int srow = tid >> 1;
    const int sko  = (tid & 1) * 16;

    for (int k0 = 0; k0 < K; k0 += 32) {
        {
            int grow = rowBase + srow;
            float4 v0 = make_float4(0.f, 0.f, 0.f, 0.f), v1 = v0;
            if (grow < Mrows) {
                const float4* pa0 = (const float4*)(A0 + (size_t)grow * K + k0 + sko);
                v0 = pa0[0]; v1 = pa0[1];
            }
            *(float4*)&As0[srow][sko]     = v0;
            *(float4*)&As0[srow][sko + 8] = v1;
        }
        {
            const float4* pb0 = (const float4*)(B0 + (size_t)(colBase + srow) * K + k0 + sko);
            float4 v0 = pb0[0], v1 = pb0[1];
            *(float4*)&Bs0[srow][sko]     = v0;
            *(float4*)&Bs0[srow][sko + 8] = v1;
        }
        __syncthreads();

        half8 a0[4], b0[4];
        #pragma unroll
        for (int i = 0; i < 4; ++i) {
            a0[i] = *(const half8*)&As0[wm + i * 16 + lm][kq];
            b0[i] = *(const half8*)&Bs0[wn + i * 16 + lm][kq];
        }
        #pragma unroll
        for (int i = 0; i < 4; ++i)
            #pragma unroll
            for (int j = 0; j < 4; ++j)
                acc[i][j] = __builtin_amdgcn_mfma_f32_16x16x32_f16(a0[i], b0[j], acc[i][j], 0, 0, 0);
        __syncthreads();
    }

    const int cq = (lane >> 4) * 4;
    #pragma unroll
    for (int j = 0; j < 4; ++j) {
        int col = colBase + wn + j * 16 + lm;
        float bv = bias[col];
        #pragma unroll
        for (int i = 0; i < 4; ++i) {
            #pragma unroll
            for (int r = 0; r < 4; ++r) {
                int grow = rowBase + wm + i * 16 + cq + r;
                if (grow < Mrows)
                    C[(size_t)grow * N + col] = acc[i][j][r] + bv;
            }
        }
    }
}

// ---------------- CSR build ----------------

__global__ void k_build_edges(const int* __restrict__ ei, int* __restrict__ src,
                              int* __restrict__ dst) {
    int i = blockIdx.x * 256 + threadIdx.x;
    if (i < NE) { src[i] = ei[i]; dst[i] = ei[NE + i]; }
    else if (i < NEE) { src[i] = i - NE; dst[i] = i - NE; }
}

__global__ void k_zero32(unsigned int* __restrict__ p, int n) {
    int i = blockIdx.x * 256 + threadIdx.x;
    if (i < n) p[i] = 0u;
}

__global__ void k_count(const int* __restrict__ dst, int* __restrict__ cnt) {
    int i = blockIdx.x * 256 + threadIdx.x;
    if (i < NEE) atomicAdd(&cnt[dst[i]], 1);
}

__global__ __launch_bounds__(256) void k_scan(const int* __restrict__ cnt,
                                              int* __restrict__ off, int* __restrict__ cur) {
    __shared__ int partial[256];
    __shared__ int ppre[257];
    int t = threadIdx.x;
    const int chunk = (NN + 255) / 256;
    int lo = t * chunk, hi = min(NN, (t + 1) * chunk);
    int s = 0;
    for (int i = lo; i < hi; ++i) s += cnt[i];
    partial[t] = s;
    __syncthreads();
    if (t == 0) {
        int acc = 0;
        for (int i = 0; i < 256; ++i) { ppre[i] = acc; acc += partial[i]; }
        ppre[256] = acc;
    }
    __syncthreads();
    int acc = ppre[t];
    for (int i = lo; i < hi; ++i) { off[i] = acc; cur[i] = acc; acc += cnt[i]; }
    if (t == 0) off[NN] = ppre[256];
}

__global__ void k_fill(const int* __restrict__ src, const int* __restrict__ dst,
                       int* __restrict__ cur, int* __restrict__ slist) {
    int e = blockIdx.x * 256 + threadIdx.x;
    if (e < NEE) { int p = atomicAdd(&cur[dst[e]], 1); slist[p] = src[e]; }
}

// ---------------- fused GATv2 edge pipeline ----------------
template<int C>
__global__ __launch_bounds__(256) void k_gat_fused(
    const float* __restrict__ xl, const float* __restrict__ xr,
    const float* __restrict__ att, const int* __restrict__ eoff,
    const int* __restrict__ slist, const float* __restrict__ bias,
    float* __restrict__ out)
{
    constexpr int NQ = C / 256;
    __shared__ float red[NH * C];
    const int n = blockIdx.x;
    const int h = threadIdx.x >> 6;
    const int lane = threadIdx.x & 63;

    float4 xr_reg[NQ], att_reg[NQ], acc[NQ];
    {
        const float* xrow = xr + (size_t)n * (NH * C) + h * C;
        const float* ah   = att + h * C;
        #pragma unroll
        for (int q = 0; q < NQ; ++q) {
            int off = q * 256 + lane * 4;
            xr_reg[q]  = *(const float4*)(xrow + off);
            att_reg[q] = *(const float4*)(ah + off);
            acc[q] = make_float4(0.f, 0.f, 0.f, 0.f);
        }
    }
    float m = -INFINITY, den = 0.f;
    const int start = eoff[n], end = eoff[n + 1];

    for (int j = start; j < end; ++j) {
        int s = slist[j];
        const float* xlr = xl + (size_t)s * (NH * C) + h * C;
        float4 xv[NQ];
        float ps = 0.f;
        #pragma unroll
        for (int q = 0; q < NQ; ++q) {
            xv[q] = *(const float4*)(xlr + q * 256 + lane * 4);
            float vx = xv[q].x + xr_reg[q].x;
            float vy = xv[q].y + xr_reg[q].y;
            float vz = xv[q].z + xr_reg[q].z;
            float vw = xv[q].w + xr_reg[q].w;
            vx = vx > 0.f ? vx : 0.2f * vx;
            vy = vy > 0.f ? vy : 0.2f * vy;
            vz = vz > 0.f ? vz : 0.2f * vz;
            vw = vw > 0.f ? vw : 0.2f * vw;
            ps = fmaf(vx, att_reg[q].x, ps);
            ps = fmaf(vy, att_reg[q].y, ps);
            ps = fmaf(vz, att_reg[q].z, ps);
            ps = fmaf(vw, att_reg[q].w, ps);
        }
        ps = waveSum(ps);
        float m_new = fmaxf(m, ps);
        float scale = expf(m - m_new);
        float ex = expf(ps - m_new);
        den = den * scale + ex;
        m = m_new;
        #pragma unroll
        for (int q = 0; q < NQ; ++q) {
            acc[q].x = fmaf(ex, xv[q].x, acc[q].x * scale);
            acc[q].y = fmaf(ex, xv[q].y, acc[q].y * scale);
            acc[q].z = fmaf(ex, xv[q].z, acc[q].z * scale);
            acc[q].w = fmaf(ex, xv[q].w, acc[q].w * scale);
        }
    }

    float inv = 1.f / (den + 1e-16f);
    #pragma unroll
    for (int q = 0; q < NQ; ++q) {
        int off = q * 256 + lane * 4;
        float4 r;
        r.x = acc[q].x * inv; r.y = acc[q].y * inv;
        r.z = acc[q].z * inv; r.w = acc[q].w * inv;
        *(float4*)&red[h * C + off] = r;
    }
    __syncthreads();

    int t = threadIdx.x;
    for (int c4 = t; c4 < C / 4; c4 += 256) {
        int c = c4 * 4;
        float4 r0 = *(const float4*)&red[0 * C + c];
        float4 r1 = *(const float4*)&red[1 * C + c];
        float4 r2 = *(const float4*)&red[2 * C + c];
        float4 r3 = *(const float4*)&red[3 * C + c];
        float4 bv = *(const float4*)(bias + c);
        float4 o;
        o.x = fmaxf((r0.x + r1.x + r2.x + r3.x) * 0.25f + bv.x, 0.f);
        o.y = fmaxf((r0.y + r1.y + r2.y + r3.y) * 0.25f + bv.y, 0.f);
        o.z = fmaxf((r0.z + r1.z + r2.z + r3.z) * 0.25f + bv.z, 0.f);
        o.w = fmaxf((r0.w + r1.w + r2.w + r3.w) * 0.25f + bv.w, 0.f);
        *(float4*)(out + (size_t)n * C + c) = o;
    }
}

// ---------------- gate + pool + MLP ----------------

__global__ __launch_bounds__(128) void k_gate(
    const float* __restrict__ x, const float* __restrict__ Wg0,
    const float* __restrict__ bg0, const float* __restrict__ Wg1,
    const float* __restrict__ bg1, float* __restrict__ g)
{
    int n = blockIdx.x;
    int t = threadIdx.x;
    __shared__ float xs[256];
    __shared__ float wsum[2];
    const float* xp = x + (size_t)n * 256;
    xs[t] = xp[t]; xs[t + 128] = xp[t + 128];
    __syncthreads();
    float acc = bg0[t];
    for (int k = 0; k < 256; ++k) acc = fmaf(xs[k], Wg0[k * 128 + t], acc);
    acc = acc > 0.f ? acc : 0.f;
    float prod = acc * Wg1[t];
    prod = waveSum(prod);
    if ((t & 63) == 0) wsum[t >> 6] = prod;
    __syncthreads();
    if (t == 0) g[n] = wsum[0] + wsum[1] + bg1[0];
}

__global__ void k_group_bounds(const int* __restrict__ batch, int* __restrict__ gstart,
                               int* __restrict__ gend) {
    int n = blockIdx.x * 256 + threadIdx.x;
    if (n >= NN) return;
    int b = batch[n];
    if (n == 0 || batch[n - 1] != b) gstart[b] = n;
    if (n == NN - 1 || batch[n + 1] != b) gend[b] = n + 1;
}

__global__ __launch_bounds__(256) void k_pool(
    const float* __restrict__ x, const float* __restrict__ g,
    const int* __restrict__ gstart, const int* __restrict__ gend,
    float* __restrict__ hpool)
{
    int gi = blockIdx.x;
    int t = threadIdx.x;
    int s0 = gstart[gi], e0 = gend[gi];
    __shared__ float red[4];
    float mx = -1e30f;
    for (int n = s0 + t; n < e0; n += 256) mx = fmaxf(mx, g[n]);
    float wm = waveMax(mx);
    if ((t & 63) == 0) red[t >> 6] = wm;
    __syncthreads();
    float m = fmaxf(fmaxf(red[0], red[1]), fmaxf(red[2], red[3]));
    __syncthreads();
    float sm = 0.f;
    for (int n = s0 + t; n < e0; n += 256) sm += expf(g[n] - m);
    sm = waveSum(sm);
    if ((t & 63) == 0) red[t >> 6] = sm;
    __syncthreads();
    float den = red[0] + red[1] + red[2] + red[3] + 1e-16f;
    float acc = 0.f;
    for (int n = s0; n < e0; ++n) {
        float w = expf(g[n] - m) / den;
        acc = fmaf(w, x[(size_t)n * 256 + t], acc);
    }
    hpool[gi * 256 + t] = acc;
}

__global__ __launch_bounds__(256) void k_mlp(
    const float* __restrict__ hpool,
    const float* __restrict__ Wm0, const float* __restrict__ bm0,
    const float* __restrict__ Wm1, const float* __restrict__ bm1,
    const float* __restrict__ Wm2, const float* __restrict__ bm2,
    const float* __restrict__ Wm3, const float* __restrict__ bm3,
    const float* __restrict__ Wm4, const float* __restrict__ bm4,
    float* __restrict__ out)
{
    __shared__ float bufA[8 * 256];
    __shared__ float bufB[8 * 128];
    int t = threadIdx.x;
    for (int i = t; i < 8 * 256; i += 256) bufA[i] = hpool[i];
    __syncthreads();
    for (int i = t; i < 8 * 128; i += 256) {
        int r = i >> 7, c = i & 127;
        float acc = bm0[c];
        for (int k = 0; k < 256; ++k) acc = fmaf(bufA[r * 256 + k], Wm0[k * 128 + c], acc);
        bufB[i] = fmaxf(acc, 0.f);
    }
    __syncthreads();
    for (int i = t; i < 8 * 64; i += 256) {
        int r = i >> 6, c = i & 63;
        float acc = bm1[c];
        for (int k = 0; k < 128; ++k) acc = fmaf(bufB[r * 128 + k], Wm1[k * 64 + c], acc);
        bufA[i] = fmaxf(acc, 0.f);
    }
    __syncthreads();
    for (int i = t; i < 8 * 32; i += 256) {
        int r = i >> 5, c = i & 31;
        float acc = bm2[c];
        for (int k = 0; k < 64; ++k) acc = fmaf(bufA[r * 64 + k], Wm2[k * 32 + c], acc);
        bufB[i] = fmaxf(acc, 0.f);
    }
    __syncthreads();
    for (int i = t; i < 8 * 16; i += 256) {
        int r = i >> 4, c = i & 15;
        float acc = bm3[c];
        for (int k = 0; k < 32; ++k) acc = fmaf(bufB[r * 32 + k], Wm3[k * 16 + c], acc);
        bufA[i] = fmaxf(acc, 0.f);
    }
    __syncthreads();
    if (t < 8) {
        float acc = bm4[0];
        for (int k = 0; k < 16; ++k) acc = fmaf(bufA[t * 16 + k], Wm4[k], acc);
        out[t] = acc;
    }
}

// ---------------- host orchestration ----------------

static void run_gat_layer(const float* xin, int K, int C,
                          const float* Wl, const float* bl,
                          const float* Wr, const float* br,
                          const float* att, const float* bias,
                          _Float16* a0p, _Float16* wb0,
                          float* xl, float* xr,
                          const int* eoff, const int* slist,
                          float* xout, hipStream_t stream)
{
    int HC = NH * C;
    int nA = NN * K;
    k_cvtA<<<(nA + 255) / 256, 256, 0, stream>>>(xin, a0p, nA);
    dim3 ggrid(HC / 128, (NN + 127) / 128);
    dim3 tgrid(HC / 32, K / 32);
    k_cvtWT<<<tgrid, 256, 0, stream>>>(Wl, wb0, K, HC);
    gemm_mfma_f16<<<ggrid, 256, 0, stream>>>(a0p, wb0, bl, xl, NN, K, HC);
    k_cvtWT<<<tgrid, 256, 0, stream>>>(Wr, wb0, K, HC);
    gemm_mfma_f16<<<ggrid, 256, 0, stream>>>(a0p, wb0, br, xr, NN, K, HC);

    if (C == 1024)
        k_gat_fused<1024><<<NN, 256, 0, stream>>>(xl, xr, att, eoff, slist, bias, xout);
    else if (C == 512)
        k_gat_fused<512><<<NN, 256, 0, stream>>>(xl, xr, att, eoff, slist, bias, xout);
    else
        k_gat_fused<256><<<NN, 256, 0, stream>>>(xl, xr, att, eoff, slist, bias, xout);
}

extern "C" void kernel_launch(void* const* d_in, const int* in_sizes, int n_in,
                              void* d_out, int out_size, void* d_ws, size_t ws_size,
                              hipStream_t stream) {
    const float* x      = (const float*)d_in[0];
    const int* ei       = (const int*)d_in[1];
    const int* batch    = (const int*)d_in[2];
    const float* Wl1 = (const float*)d_in[3];  const float* bl1 = (const float*)d_in[4];
    const float* Wr1 = (const float*)d_in[5];  const float* br1 = (const float*)d_in[6];
    const float* att1= (const float*)d_in[7];  const float* b1  = (const float*)d_in[8];
    const float* Wl2 = (const float*)d_in[9];  const float* bl2 = (const float*)d_in[10];
    const float* Wr2 = (const float*)d_in[11]; const float* br2 = (const float*)d_in[12];
    const float* att2= (const float*)d_in[13]; const float* b2  = (const float*)d_in[14];
    const float* Wl3 = (const float*)d_in[15]; const float* bl3 = (const float*)d_in[16];
    const float* Wr3 = (const float*)d_in[17]; const float* br3 = (const float*)d_in[18];
    const float* att3= (const float*)d_in[19]; const float* b3  = (const float*)d_in[20];
    const float* Wm0 = (const float*)d_in[21]; const float* bm0 = (const float*)d_in[22];
    const float* Wm1 = (const float*)d_in[23]; const float* bm1 = (const float*)d_in[24];
    const float* Wm2 = (const float*)d_in[25]; const float* bm2 = (const float*)d_in[26];
    const float* Wm3 = (const float*)d_in[27]; const float* bm3 = (const float*)d_in[28];
    const float* Wm4 = (const float*)d_in[29]; const float* bm4 = (const float*)d_in[30];
    const float* Wg0 = (const float*)d_in[31]; const float* bg0 = (const float*)d_in[32];
    const float* Wg1 = (const float*)d_in[33]; const float* bg1 = (const float*)d_in[34];
    float* out = (float*)d_out;

    // workspace carve (float units = 4B)
    float* ws = (float*)d_ws;
    size_t o = 0;
    float* xl    = ws + o; o += (size_t)NN * 4096;
    float* xr    = ws + o; o += (size_t)NN * 4096;
    float* x1    = ws + o; o += (size_t)NN * 1024;
    float* x2    = ws + o; o += (size_t)NN * 512;
    float* x3    = ws + o; o += (size_t)NN * 256;
    int* srcA    = (int*)(ws + o); o += NEE;
    int* dstA    = (int*)(ws + o); o += NEE;
    int* cnt     = (int*)(ws + o); o += NN;
    int* eoff    = (int*)(ws + o); o += NN + 1;
    int* cur     = (int*)(ws + o); o += NN;
    int* slist   = (int*)(ws + o); o += NEE;
    float* g     = ws + o; o += NN;
    int* gstart  = (int*)(ws + o); o += NG;
    int* gend    = (int*)(ws + o); o += NG;
    float* hpool = ws + o; o += NG * 256;
    _Float16* a0p = (_Float16*)(ws + o); o += (size_t)NN * 1536 / 2;
    _Float16* wb0 = (_Float16*)(ws + o); o += (size_t)1536 * 4096 / 2;

    // build CSR by dst (slist holds src node ids)
    int ebB = (NEE + 255) / 256;
    k_build_edges<<<ebB, 256, 0, stream>>>(ei, srcA, dstA);
    k_zero32<<<(NN + 255) / 256, 256, 0, stream>>>((unsigned int*)cnt, NN);
    k_count<<<ebB, 256, 0, stream>>>(dstA, cnt);
    k_scan<<<1, 256, 0, stream>>>(cnt, eoff, cur);
    k_fill<<<ebB, 256, 0, stream>>>(srcA, dstA, cur, slist);

    // three GATv2 layers
    run_gat_layer(x,  1536, 1024, Wl1, bl1, Wr1, br1, att1, b1,
                  a0p, wb0, xl, xr, eoff, slist, x1, stream);
    run_gat_layer(x1, 1024, 512,  Wl2, bl2, Wr2, br2, att2, b2,
                  a0p, wb0, xl, xr, eoff, slist, x2, stream);
    run_gat_layer(x2, 512,  256,  Wl3, bl3, Wr3, br3, att3, b3,
                  a0p, wb0, xl, xr, eoff, slist, x3, stream);

    // gate + pool + MLP
    k_gate<<<NN, 128, 0, stream>>>(x3, Wg0, bg0, Wg1, bg1, g);
    k_zero32<<<1, 64, 0, stream>>>((unsigned int*)gstart, 2 * NG);
    k_group_bounds<<<(NN + 255) / 256, 256, 0, stream>>>(batch, gstart, gend);
    k_pool<<<NG, 256, 0, stream>>>(x3, g, gstart, gend, hpool);
    k_mlp<<<1, 256, 0, stream>>>(hpool, Wm0, bm0, Wm1, bm1, Wm2, bm2,
                                 Wm3, bm3, Wm4, bm4, out);
}

// Round 5
// 1011.062 us; speedup vs baseline: 3.2648x; 1.1450x over previous
//
#include <hip/hip_runtime.h>
#include <math.h>

// Problem constants (from reference)
#define NN 5000
#define NE 50000
#define NEE 55000   // edges + self loops
#define NG 8
#define NH 4

typedef __attribute__((ext_vector_type(8))) _Float16 half8;
typedef __attribute__((ext_vector_type(4))) float floatx4;

// ---------------- utility device functions ----------------

__device__ inline float waveSum(float v) {
    #pragma unroll
    for (int o = 32; o > 0; o >>= 1) v += __shfl_xor(v, o, 64);
    return v;
}
__device__ inline float waveMax(float v) {
    #pragma unroll
    for (int o = 32; o > 0; o >>= 1) v = fmaxf(v, __shfl_xor(v, o, 64));
    return v;
}

// ---------------- fp32 -> fp16 conversion ----------------

__global__ void k_cvtA(const float* __restrict__ X, _Float16* __restrict__ A0, int n) {
    int i = blockIdx.x * 256 + threadIdx.x;
    if (i >= n) return;
    A0[i] = (_Float16)X[i];
}

// W (K x M fp32) -> B0 fp16 TRANSPOSED to (M x K)
__global__ __launch_bounds__(256) void k_cvtWT(const float* __restrict__ W,
        _Float16* __restrict__ B0, int K, int M)
{
    __shared__ float tile[32][33];
    int m0 = blockIdx.x * 32, k0 = blockIdx.y * 32;
    int tx = threadIdx.x & 31, ty = threadIdx.x >> 5;
    #pragma unroll
    for (int i = 0; i < 4; ++i)
        tile[ty + 8 * i][tx] = W[(size_t)(k0 + ty + 8 * i) * M + m0 + tx];
    __syncthreads();
    #pragma unroll
    for (int i = 0; i < 4; ++i) {
        int mm = ty + 8 * i, kk = tx;
        B0[(size_t)(m0 + mm) * K + kk + k0] = (_Float16)tile[kk][mm];
    }
}

// ---------------- MFMA fp16 GEMM (single product) ----------------
#define LDSPAD 40

__global__ __launch_bounds__(256) void gemm_mfma_f16(
    const _Float16* __restrict__ A0, const _Float16* __restrict__ B0,
    const float* __restrict__ bias, float* __restrict__ C,
    int Mrows, int K, int N)
{
    __shared__ _Float16 As0[128][LDSPAD];
    __shared__ _Float16 Bs0[128][LDSPAD];

    const int tid = threadIdx.x;
    const int wave = tid >> 6;
    const int lane = tid & 63;
    const int wm = (wave >> 1) * 64;
    const int wn = (wave & 1) * 64;
    const int lm = lane & 15;
    const int kq = (lane >> 4) * 8;
    const int rowBase = blockIdx.y * 128;
    const int colBase = blockIdx.x * 128;

    floatx4 acc[4][4];
    #pragma unroll
    for (int i = 0; i < 4; ++i)
        #pragma unroll
        for (int j = 0; j < 4; ++j)
            acc[i][j] = (floatx4){0.f, 0.f, 0.f, 0.f};

    const int srow = tid >> 1;
    const int sko  = (tid & 1) * 16;

    for (int k0 = 0; k0 < K; k0 += 32) {
        {
            int grow = rowBase + srow;
            float4 v0 = make_float4(0.f, 0.f, 0.f, 0.f), v1 = v0;
            if (grow < Mrows) {
                const float4* pa0 = (const float4*)(A0 + (size_t)grow * K + k0 + sko);
                v0 = pa0[0]; v1 = pa0[1];
            }
            *(float4*)&As0[srow][sko]     = v0;
            *(float4*)&As0[srow][sko + 8] = v1;
        }
        {
            const float4* pb0 = (const float4*)(B0 + (size_t)(colBase + srow) * K + k0 + sko);
            float4 v0 = pb0[0], v1 = pb0[1];
            *(float4*)&Bs0[srow][sko]     = v0;
            *(float4*)&Bs0[srow][sko + 8] = v1;
        }
        __syncthreads();

        half8 a0[4], b0[4];
        #pragma unroll
        for (int i = 0; i < 4; ++i) {
            a0[i] = *(const half8*)&As0[wm + i * 16 + lm][kq];
            b0[i] = *(const half8*)&Bs0[wn + i * 16 + lm][kq];
        }
        #pragma unroll
        for (int i = 0; i < 4; ++i)
            #pragma unroll
            for (int j = 0; j < 4; ++j)
                acc[i][j] = __builtin_amdgcn_mfma_f32_16x16x32_f16(a0[i], b0[j], acc[i][j], 0, 0, 0);
        __syncthreads();
    }

    const int cq = (lane >> 4) * 4;
    #pragma unroll
    for (int j = 0; j < 4; ++j) {
        int col = colBase + wn + j * 16 + lm;
        float bv = bias[col];
        #pragma unroll
        for (int i = 0; i < 4; ++i) {
            #pragma unroll
            for (int r = 0; r < 4; ++r) {
                int grow = rowBase + wm + i * 16 + cq + r;
                if (grow < Mrows)
                    C[(size_t)grow * N + col] = acc[i][j][r] + bv;
            }
        }
    }
}

// ---------------- CSR build ----------------

__global__ void k_build_edges(const int* __restrict__ ei, int* __restrict__ src,
                              int* __restrict__ dst) {
    int i = blockIdx.x * 256 + threadIdx.x;
    if (i < NE) { src[i] = ei[i]; dst[i] = ei[NE + i]; }
    else if (i < NEE) { src[i] = i - NE; dst[i] = i - NE; }
}

__global__ void k_zero32(unsigned int* __restrict__ p, int n) {
    int i = blockIdx.x * 256 + threadIdx.x;
    if (i < n) p[i] = 0u;
}

__global__ void k_count(const int* __restrict__ dst, int* __restrict__ cnt) {
    int i = blockIdx.x * 256 + threadIdx.x;
    if (i < NEE) atomicAdd(&cnt[dst[i]], 1);
}

__global__ __launch_bounds__(256) void k_scan(const int* __restrict__ cnt,
                                              int* __restrict__ off, int* __restrict__ cur) {
    __shared__ int partial[256];
    __shared__ int ppre[257];
    int t = threadIdx.x;
    const int chunk = (NN + 255) / 256;
    int lo = t * chunk, hi = min(NN, (t + 1) * chunk);
    int s = 0;
    for (int i = lo; i < hi; ++i) s += cnt[i];
    partial[t] = s;
    __syncthreads();
    if (t == 0) {
        int acc = 0;
        for (int i = 0; i < 256; ++i) { ppre[i] = acc; acc += partial[i]; }
        ppre[256] = acc;
    }
    __syncthreads();
    int acc = ppre[t];
    for (int i = lo; i < hi; ++i) { off[i] = acc; cur[i] = acc; acc += cnt[i]; }
    if (t == 0) off[NN] = ppre[256];
}

__global__ void k_fill(const int* __restrict__ src, const int* __restrict__ dst,
                       int* __restrict__ cur, int* __restrict__ slist) {
    int e = blockIdx.x * 256 + threadIdx.x;
    if (e < NEE) { int p = atomicAdd(&cur[dst[e]], 1); slist[p] = src[e]; }
}

// ---------------- fused GATv2 edge pipeline ----------------
template<int C>
__global__ __launch_bounds__(256) void k_gat_fused(
    const float* __restrict__ xl, const float* __restrict__ xr,
    const float* __restrict__ att, const int* __restrict__ eoff,
    const int* __restrict__ slist, const float* __restrict__ bias,
    float* __restrict__ out)
{
    constexpr int NQ = C / 256;
    __shared__ float red[NH * C];
    const int n = blockIdx.x;
    const int h = threadIdx.x >> 6;
    const int lane = threadIdx.x & 63;

    float4 xr_reg[NQ], att_reg[NQ], acc[NQ];
    {
        const float* xrow = xr + (size_t)n * (NH * C) + h * C;
        const float* ah   = att + h * C;
        #pragma unroll
        for (int q = 0; q < NQ; ++q) {
            int off = q * 256 + lane * 4;
            xr_reg[q]  = *(const float4*)(xrow + off);
            att_reg[q] = *(const float4*)(ah + off);
            acc[q] = make_float4(0.f, 0.f, 0.f, 0.f);
        }
    }
    float m = -INFINITY, den = 0.f;
    const int start = eoff[n], end = eoff[n + 1];

    for (int j = start; j < end; ++j) {
        int s = slist[j];
        const float* xlr = xl + (size_t)s * (NH * C) + h * C;
        float4 xv[NQ];
        float ps = 0.f;
        #pragma unroll
        for (int q = 0; q < NQ; ++q) {
            xv[q] = *(const float4*)(xlr + q * 256 + lane * 4);
            float vx = xv[q].x + xr_reg[q].x;
            float vy = xv[q].y + xr_reg[q].y;
            float vz = xv[q].z + xr_reg[q].z;
            float vw = xv[q].w + xr_reg[q].w;
            vx = vx > 0.f ? vx : 0.2f * vx;
            vy = vy > 0.f ? vy : 0.2f * vy;
            vz = vz > 0.f ? vz : 0.2f * vz;
            vw = vw > 0.f ? vw : 0.2f * vw;
            ps = fmaf(vx, att_reg[q].x, ps);
            ps = fmaf(vy, att_reg[q].y, ps);
            ps = fmaf(vz, att_reg[q].z, ps);
            ps = fmaf(vw, att_reg[q].w, ps);
        }
        ps = waveSum(ps);
        float m_new = fmaxf(m, ps);
        float scale = expf(m - m_new);
        float ex = expf(ps - m_new);
        den = den * scale + ex;
        m = m_new;
        #pragma unroll
        for (int q = 0; q < NQ; ++q) {
            acc[q].x = fmaf(ex, xv[q].x, acc[q].x * scale);
            acc[q].y = fmaf(ex, xv[q].y, acc[q].y * scale);
            acc[q].z = fmaf(ex, xv[q].z, acc[q].z * scale);
            acc[q].w = fmaf(ex, xv[q].w, acc[q].w * scale);
        }
    }

    float inv = 1.f / (den + 1e-16f);
    #pragma unroll
    for (int q = 0; q < NQ; ++q) {
        int off = q * 256 + lane * 4;
        float4 r;
        r.x = acc[q].x * inv; r.y = acc[q].y * inv;
        r.z = acc[q].z * inv; r.w = acc[q].w * inv;
        *(float4*)&red[h * C + off] = r;
    }
    __syncthreads();

    int t = threadIdx.x;
    for (int c4 = t; c4 < C / 4; c4 += 256) {
        int c = c4 * 4;
        float4 r0 = *(const float4*)&red[0 * C + c];
        float4 r1 = *(const float4*)&red[1 * C + c];
        float4 r2 = *(const float4*)&red[2 * C + c];
        float4 r3 = *(const float4*)&red[3 * C + c];
        float4 bv = *(const float4*)(bias + c);
        float4 o;
        o.x = fmaxf((r0.x + r1.x + r2.x + r3.x) * 0.25f + bv.x, 0.f);
        o.y = fmaxf((r0.y + r1.y + r2.y + r3.y) * 0.25f + bv.y, 0.f);
        o.z = fmaxf((r0.z + r1.z + r2.z + r3.z) * 0.25f + bv.z, 0.f);
        o.w = fmaxf((r0.w + r1.w + r2.w + r3.w) * 0.25f + bv.w, 0.f);
        *(float4*)(out + (size_t)n * C + c) = o;
    }
}

// ---------------- gate + pool + MLP ----------------

__global__ __launch_bounds__(128) void k_gate(
    const float* __restrict__ x, const float* __restrict__ Wg0,
    const float* __restrict__ bg0, const float* __restrict__ Wg1,
    const float* __restrict__ bg1, float* __restrict__ g)
{
    int n = blockIdx.x;
    int t = threadIdx.x;
    __shared__ float xs[256];
    __shared__ float wsum[2];
    const float* xp = x + (size_t)n * 256;
    xs[t] = xp[t]; xs[t + 128] = xp[t + 128];
    __syncthreads();
    float acc = bg0[t];
    for (int k = 0; k < 256; ++k) acc = fmaf(xs[k], Wg0[k * 128 + t], acc);
    acc = acc > 0.f ? acc : 0.f;
    float prod = acc * Wg1[t];
    prod = waveSum(prod);
    if ((t & 63) == 0) wsum[t >> 6] = prod;
    __syncthreads();
    if (t == 0) g[n] = wsum[0] + wsum[1] + bg1[0];
}

__global__ void k_group_bounds(const int* __restrict__ batch, int* __restrict__ gstart,
                               int* __restrict__ gend) {
    int n = blockIdx.x * 256 + threadIdx.x;
    if (n >= NN) return;
    int b = batch[n];
    if (n == 0 || batch[n - 1] != b) gstart[b] = n;
    if (n == NN - 1 || batch[n + 1] != b) gend[b] = n + 1;
}

// per-group softmax stats: m[g], invden[g]
__global__ __launch_bounds__(256) void k_pool_stats(
    const float* __restrict__ g, const int* __restrict__ gstart,
    const int* __restrict__ gend, float* __restrict__ mOut,
    float* __restrict__ invdenOut)
{
    int gi = blockIdx.x;
    int t = threadIdx.x;
    int s0 = gstart[gi], e0 = gend[gi];
    __shared__ float red[4];
    float mx = -1e30f;
    for (int n = s0 + t; n < e0; n += 256) mx = fmaxf(mx, g[n]);
    float wm = waveMax(mx);
    if ((t & 63) == 0) red[t >> 6] = wm;
    __syncthreads();
    float m = fmaxf(fmaxf(red[0], red[1]), fmaxf(red[2], red[3]));
    __syncthreads();
    float sm = 0.f;
    for (int n = s0 + t; n < e0; n += 256) sm += expf(g[n] - m);
    sm = waveSum(sm);
    if ((t & 63) == 0) red[t >> 6] = sm;
    __syncthreads();
    if (t == 0) {
        float den = red[0] + red[1] + red[2] + red[3] + 1e-16f;
        mOut[gi] = m;
        invdenOut[gi] = 1.f / den;
    }
}

// weighted-sum accumulation, parallel over node chunks; thread t owns channel t
#define PCH 16
__global__ __launch_bounds__(256) void k_pool_acc(
    const float* __restrict__ x, const float* __restrict__ g,
    const int* __restrict__ batch, const float* __restrict__ m,
    const float* __restrict__ invden, float* __restrict__ hpool)
{
    int base = blockIdx.x * PCH;
    int t = threadIdx.x;
    float acc = 0.f;
    int cur = -1;
    for (int i = 0; i < PCH; ++i) {
        int n = base + i;
        if (n >= NN) break;
        int b = batch[n];
        if (b != cur) {
            if (cur >= 0) atomicAdd(&hpool[cur * 256 + t], acc);
            cur = b; acc = 0.f;
        }
        float w = expf(g[n] - m[b]) * invden[b];
        acc = fmaf(w, x[(size_t)n * 256 + t], acc);
    }
    if (cur >= 0) atomicAdd(&hpool[cur * 256 + t], acc);
}

__global__ __launch_bounds__(256) void k_mlp(
    const float* __restrict__ hpool,
    const float* __restrict__ Wm0, const float* __restrict__ bm0,
    const float* __restrict__ Wm1, const float* __restrict__ bm1,
    const float* __restrict__ Wm2, const float* __restrict__ bm2,
    const float* __restrict__ Wm3, const float* __restrict__ bm3,
    const float* __restrict__ Wm4, const float* __restrict__ bm4,
    float* __restrict__ out)
{
    __shared__ float bufA[8 * 256];
    __shared__ float bufB[8 * 128];
    int t = threadIdx.x;
    for (int i = t; i < 8 * 256; i += 256) bufA[i] = hpool[i];
    __syncthreads();
    for (int i = t; i < 8 * 128; i += 256) {
        int r = i >> 7, c = i & 127;
        float acc = bm0[c];
        for (int k = 0; k < 256; ++k) acc = fmaf(bufA[r * 256 + k], Wm0[k * 128 + c], acc);
        bufB[i] = fmaxf(acc, 0.f);
    }
    __syncthreads();
    for (int i = t; i < 8 * 64; i += 256) {
        int r = i >> 6, c = i & 63;
        float acc = bm1[c];
        for (int k = 0; k < 128; ++k) acc = fmaf(bufB[r * 128 + k], Wm1[k * 64 + c], acc);
        bufA[i] = fmaxf(acc, 0.f);
    }
    __syncthreads();
    for (int i = t; i < 8 * 32; i += 256) {
        int r = i >> 5, c = i & 31;
        float acc = bm2[c];
        for (int k = 0; k < 64; ++k) acc = fmaf(bufA[r * 64 + k], Wm2[k * 32 + c], acc);
        bufB[i] = fmaxf(acc, 0.f);
    }
    __syncthreads();
    for (int i = t; i < 8 * 16; i += 256) {
        int r = i >> 4, c = i & 15;
        float acc = bm3[c];
        for (int k = 0; k < 32; ++k) acc = fmaf(bufB[r * 32 + k], Wm3[k * 16 + c], acc);
        bufA[i] = fmaxf(acc, 0.f);
    }
    __syncthreads();
    if (t < 8) {
        float acc = bm4[0];
        for (int k = 0; k < 16; ++k) acc = fmaf(bufA[t * 16 + k], Wm4[k], acc);
        out[t] = acc;
    }
}

// ---------------- host orchestration ----------------

static void run_gat_layer(const float* xin, int K, int C,
                          const float* Wl, const float* bl,
                          const float* Wr, const float* br,
                          const float* att, const float* bias,
                          _Float16* a0p, _Float16* wb0,
                          float* xl, float* xr,
                          const int* eoff, const int* slist,
                          float* xout, hipStream_t stream)
{
    int HC = NH * C;
    int nA = NN * K;
    k_cvtA<<<(nA + 255) / 256, 256, 0, stream>>>(xin, a0p, nA);
    dim3 ggrid(HC / 128, (NN + 127) / 128);
    dim3 tgrid(HC / 32, K / 32);
    k_cvtWT<<<tgrid, 256, 0, stream>>>(Wl, wb0, K, HC);
    gemm_mfma_f16<<<ggrid, 256, 0, stream>>>(a0p, wb0, bl, xl, NN, K, HC);
    k_cvtWT<<<tgrid, 256, 0, stream>>>(Wr, wb0, K, HC);
    gemm_mfma_f16<<<ggrid, 256, 0, stream>>>(a0p, wb0, br, xr, NN, K, HC);

    if (C == 1024)
        k_gat_fused<1024><<<NN, 256, 0, stream>>>(xl, xr, att, eoff, slist, bias, xout);
    else if (C == 512)
        k_gat_fused<512><<<NN, 256, 0, stream>>>(xl, xr, att, eoff, slist, bias, xout);
    else
        k_gat_fused<256><<<NN, 256, 0, stream>>>(xl, xr, att, eoff, slist, bias, xout);
}

extern "C" void kernel_launch(void* const* d_in, const int* in_sizes, int n_in,
                              void* d_out, int out_size, void* d_ws, size_t ws_size,
                              hipStream_t stream) {
    const float* x      = (const float*)d_in[0];
    const int* ei       = (const int*)d_in[1];
    const int* batch    = (const int*)d_in[2];
    const float* Wl1 = (const float*)d_in[3];  const float* bl1 = (const float*)d_in[4];
    const float* Wr1 = (const float*)d_in[5];  const float* br1 = (const float*)d_in[6];
    const float* att1= (const float*)d_in[7];  const float* b1  = (const float*)d_in[8];
    const float* Wl2 = (const float*)d_in[9];  const float* bl2 = (const float*)d_in[10];
    const float* Wr2 = (const float*)d_in[11]; const float* br2 = (const float*)d_in[12];
    const float* att2= (const float*)d_in[13]; const float* b2  = (const float*)d_in[14];
    const float* Wl3 = (const float*)d_in[15]; const float* bl3 = (const float*)d_in[16];
    const float* Wr3 = (const float*)d_in[17]; const float* br3 = (const float*)d_in[18];
    const float* att3= (const float*)d_in[19]; const float* b3  = (const float*)d_in[20];
    const float* Wm0 = (const float*)d_in[21]; const float* bm0 = (const float*)d_in[22];
    const float* Wm1 = (const float*)d_in[23]; const float* bm1 = (const float*)d_in[24];
    const float* Wm2 = (const float*)d_in[25]; const float* bm2 = (const float*)d_in[26];
    const float* Wm3 = (const float*)d_in[27]; const float* bm3 = (const float*)d_in[28];
    const float* Wm4 = (const float*)d_in[29]; const float* bm4 = (const float*)d_in[30];
    const float* Wg0 = (const float*)d_in[31]; const float* bg0 = (const float*)d_in[32];
    const float* Wg1 = (const float*)d_in[33]; const float* bg1 = (const float*)d_in[34];
    float* out = (float*)d_out;

    // workspace carve (float units = 4B)
    float* ws = (float*)d_ws;
    size_t o = 0;
    float* xl    = ws + o; o += (size_t)NN * 4096;
    float* xr    = ws + o; o += (size_t)NN * 4096;
    float* x1    = ws + o; o += (size_t)NN * 1024;
    float* x2    = ws + o; o += (size_t)NN * 512;
    float* x3    = ws + o; o += (size_t)NN * 256;
    int* srcA    = (int*)(ws + o); o += NEE;
    int* dstA    = (int*)(ws + o); o += NEE;
    int* cnt     = (int*)(ws + o); o += NN;
    int* eoff    = (int*)(ws + o); o += NN + 1;
    int* cur     = (int*)(ws + o); o += NN;
    int* slist   = (int*)(ws + o); o += NEE;
    float* g     = ws + o; o += NN;
    int* gstart  = (int*)(ws + o); o += NG;
    int* gend    = (int*)(ws + o); o += NG;
    float* gm    = ws + o; o += NG;
    float* ginv  = ws + o; o += NG;
    float* hpool = ws + o; o += NG * 256;
    _Float16* a0p = (_Float16*)(ws + o); o += (size_t)NN * 1536 / 2;
    _Float16* wb0 = (_Float16*)(ws + o); o += (size_t)1536 * 4096 / 2;

    // build CSR by dst (slist holds src node ids)
    int ebB = (NEE + 255) / 256;
    k_build_edges<<<ebB, 256, 0, stream>>>(ei, srcA, dstA);
    k_zero32<<<(NN + 255) / 256, 256, 0, stream>>>((unsigned int*)cnt, NN);
    k_count<<<ebB, 256, 0, stream>>>(dstA, cnt);
    k_scan<<<1, 256, 0, stream>>>(cnt, eoff, cur);
    k_fill<<<ebB, 256, 0, stream>>>(srcA, dstA, cur, slist);

    // three GATv2 layers
    run_gat_layer(x,  1536, 1024, Wl1, bl1, Wr1, br1, att1, b1,
                  a0p, wb0, xl, xr, eoff, slist, x1, stream);
    run_gat_layer(x1, 1024, 512,  Wl2, bl2, Wr2, br2, att2, b2,
                  a0p, wb0, xl, xr, eoff, slist, x2, stream);
    run_gat_layer(x2, 512,  256,  Wl3, bl3, Wr3, br3, att3, b3,
                  a0p, wb0, xl, xr, eoff, slist, x3, stream);

    // gate + pool + MLP
    k_gate<<<NN, 128, 0, stream>>>(x3, Wg0, bg0, Wg1, bg1, g);
    k_zero32<<<1, 64, 0, stream>>>((unsigned int*)gstart, 2 * NG);
    k_group_bounds<<<(NN + 255) / 256, 256, 0, stream>>>(batch, gstart, gend);
    k_pool_stats<<<NG, 256, 0, stream>>>(g, gstart, gend, gm, ginv);
    k_zero32<<<(NG * 256 + 255) / 256, 256, 0, stream>>>((unsigned int*)hpool, NG * 256);
    k_pool_acc<<<(NN + PCH - 1) / PCH, 256, 0, stream>>>(x3, g, batch, gm, ginv, hpool);
    k_mlp<<<1, 256, 0, stream>>>(hpool, Wm0, bm0, Wm1, bm1, Wm2, bm2,
                                 Wm3, bm3, Wm4, bm4, out);
}

// Round 6
// 989.243 us; speedup vs baseline: 3.3368x; 1.0221x over previous
//
#include <hip/hip_runtime.h>
#include <math.h>

// Problem constants (from reference)
#define NN 5000
#define NE 50000
#define NEE 55000   // edges + self loops
#define NG 8
#define NH 4

typedef __attribute__((ext_vector_type(8))) _Float16 half8;
typedef __attribute__((ext_vector_type(4))) float floatx4;

// ---------------- utility device functions ----------------

__device__ inline float waveSum(float v) {
    #pragma unroll
    for (int o = 32; o > 0; o >>= 1) v += __shfl_xor(v, o, 64);
    return v;
}
__device__ inline float waveMax(float v) {
    #pragma unroll
    for (int o = 32; o > 0; o >>= 1) v = fmaxf(v, __shfl_xor(v, o, 64));
    return v;
}

// async global->LDS DMA, 16B per lane; lds dest must be wave-uniform base
__device__ __forceinline__ void gload_lds16(const _Float16* g, _Float16* l) {
    __builtin_amdgcn_global_load_lds(
        (__attribute__((address_space(1))) void*)g,
        (__attribute__((address_space(3))) void*)l,
        16, 0, 0);
}

// ---------------- fp32 -> fp16 conversion ----------------

__global__ void k_cvtA(const float* __restrict__ X, _Float16* __restrict__ A0, int n) {
    int i = blockIdx.x * 256 + threadIdx.x;
    if (i >= n) return;
    A0[i] = (_Float16)X[i];
}

// W (K x M fp32) -> B0 fp16 TRANSPOSED to (M x K)
__global__ __launch_bounds__(256) void k_cvtWT(const float* __restrict__ W,
        _Float16* __restrict__ B0, int K, int M)
{
    __shared__ float tile[32][33];
    int m0 = blockIdx.x * 32, k0 = blockIdx.y * 32;
    int tx = threadIdx.x & 31, ty = threadIdx.x >> 5;
    #pragma unroll
    for (int i = 0; i < 4; ++i)
        tile[ty + 8 * i][tx] = W[(size_t)(k0 + ty + 8 * i) * M + m0 + tx];
    __syncthreads();
    #pragma unroll
    for (int i = 0; i < 4; ++i) {
        int mm = ty + 8 * i, kk = tx;
        B0[(size_t)(m0 + mm) * K + kk + k0] = (_Float16)tile[kk][mm];
    }
}

// ---------------- MFMA fp16 GEMM, global_load_lds staging ----------------
// C(Mrows x N) = A(Mrows x K) @ B^T + bias;  A fp16 (Mrows x K),
// B fp16 transposed (N x K).  LDS tiles UNPADDED [128][32] halfs — layout is
// dictated by global_load_lds (wave base + lane*16B); ds_read_b128 fragment
// reads hit each bank exactly 8x per wave (ideal, conflict-free).
__global__ __launch_bounds__(256) void gemm_mfma_f16(
    const _Float16* __restrict__ A0, const _Float16* __restrict__ B0,
    const float* __restrict__ bias, float* __restrict__ C,
    int Mrows, int K, int N)
{
    __shared__ __align__(16) _Float16 As0[128 * 32];
    __shared__ __align__(16) _Float16 Bs0[128 * 32];

    const int tid = threadIdx.x;
    const int wave = tid >> 6;
    const int lane = tid & 63;
    const int wm = (wave >> 1) * 64;
    const int wn = (wave & 1) * 64;
    const int lm = lane & 15;
    const int kq = (lane >> 4) * 8;
    const int rowBase = blockIdx.y * 128;
    const int colBase = blockIdx.x * 128;

    floatx4 acc[4][4];
    #pragma unroll
    for (int i = 0; i < 4; ++i)
        #pragma unroll
        for (int j = 0; j < 4; ++j)
            acc[i][j] = (floatx4){0.f, 0.f, 0.f, 0.f};

    // staging: wave w owns rows [w*32, w*32+32): two 16-row DMA issues per matrix
    const int srow = wave * 32 + (lane >> 2);   // first-half row for this lane
    const int scol = (lane & 3) * 8;            // halfs offset within row
    const _Float16* gA = A0 + (size_t)(rowBase + srow) * K + scol;
    const _Float16* gB = B0 + (size_t)(colBase + srow) * K + scol;
    const size_t rowSkip = (size_t)16 * K;
    _Float16* lA0 = &As0[(wave * 32) * 32];
    _Float16* lA1 = &As0[(wave * 32 + 16) * 32];
    _Float16* lB0 = &Bs0[(wave * 32) * 32];
    _Float16* lB1 = &Bs0[(wave * 32 + 16) * 32];

    for (int k0 = 0; k0 < K; k0 += 32) {
        gload_lds16(gA + k0, lA0);
        gload_lds16(gA + rowSkip + k0, lA1);
        gload_lds16(gB + k0, lB0);
        gload_lds16(gB + rowSkip + k0, lB1);
        __syncthreads();   // drains vmcnt -> DMA complete

        half8 a0[4], b0[4];
        #pragma unroll
        for (int i = 0; i < 4; ++i) {
            a0[i] = *(const half8*)&As0[(wm + i * 16 + lm) * 32 + kq];
            b0[i] = *(const half8*)&Bs0[(wn + i * 16 + lm) * 32 + kq];
        }
        #pragma unroll
        for (int i = 0; i < 4; ++i)
            #pragma unroll
            for (int j = 0; j < 4; ++j)
                acc[i][j] = __builtin_amdgcn_mfma_f32_16x16x32_f16(a0[i], b0[j], acc[i][j], 0, 0, 0);
        __syncthreads();
    }

    const int cq = (lane >> 4) * 4;
    #pragma unroll
    for (int j = 0; j < 4; ++j) {
        int col = colBase + wn + j * 16 + lm;
        float bv = bias[col];
        #pragma unroll
        for (int i = 0; i < 4; ++i) {
            #pragma unroll
            for (int r = 0; r < 4; ++r) {
                int grow = rowBase + wm + i * 16 + cq + r;
                if (grow < Mrows)
                    C[(size_t)grow * N + col] = acc[i][j][r] + bv;
            }
        }
    }
}

// ---------------- CSR build ----------------

__global__ void k_build_edges(const int* __restrict__ ei, int* __restrict__ src,
                              int* __restrict__ dst) {
    int i = blockIdx.x * 256 + threadIdx.x;
    if (i < NE) { src[i] = ei[i]; dst[i] = ei[NE + i]; }
    else if (i < NEE) { src[i] = i - NE; dst[i] = i - NE; }
}

__global__ void k_zero32(unsigned int* __restrict__ p, int n) {
    int i = blockIdx.x * 256 + threadIdx.x;
    if (i < n) p[i] = 0u;
}

__global__ void k_count(const int* __restrict__ dst, int* __restrict__ cnt) {
    int i = blockIdx.x * 256 + threadIdx.x;
    if (i < NEE) atomicAdd(&cnt[dst[i]], 1);
}

__global__ __launch_bounds__(256) void k_scan(const int* __restrict__ cnt,
                                              int* __restrict__ off, int* __restrict__ cur) {
    __shared__ int partial[256];
    __shared__ int ppre[257];
    int t = threadIdx.x;
    const int chunk = (NN + 255) / 256;
    int lo = t * chunk, hi = min(NN, (t + 1) * chunk);
    int s = 0;
    for (int i = lo; i < hi; ++i) s += cnt[i];
    partial[t] = s;
    __syncthreads();
    if (t == 0) {
        int acc = 0;
        for (int i = 0; i < 256; ++i) { ppre[i] = acc; acc += partial[i]; }
        ppre[256] = acc;
    }
    __syncthreads();
    int acc = ppre[t];
    for (int i = lo; i < hi; ++i) { off[i] = acc; cur[i] = acc; acc += cnt[i]; }
    if (t == 0) off[NN] = ppre[256];
}

__global__ void k_fill(const int* __restrict__ src, const int* __restrict__ dst,
                       int* __restrict__ cur, int* __restrict__ slist) {
    int e = blockIdx.x * 256 + threadIdx.x;
    if (e < NEE) { int p = atomicAdd(&cur[dst[e]], 1); slist[p] = src[e]; }
}

// ---------------- fused GATv2 edge pipeline ----------------
template<int C>
__global__ __launch_bounds__(256) void k_gat_fused(
    const float* __restrict__ xl, const float* __restrict__ xr,
    const float* __restrict__ att, const int* __restrict__ eoff,
    const int* __restrict__ slist, const float* __restrict__ bias,
    float* __restrict__ out)
{
    constexpr int NQ = C / 256;
    __shared__ float red[NH * C];
    const int n = blockIdx.x;
    const int h = threadIdx.x >> 6;
    const int lane = threadIdx.x & 63;

    float4 xr_reg[NQ], att_reg[NQ], acc[NQ];
    {
        const float* xrow = xr + (size_t)n * (NH * C) + h * C;
        const float* ah   = att + h * C;
        #pragma unroll
        for (int q = 0; q < NQ; ++q) {
            int off = q * 256 + lane * 4;
            xr_reg[q]  = *(const float4*)(xrow + off);
            att_reg[q] = *(const float4*)(ah + off);
            acc[q] = make_float4(0.f, 0.f, 0.f, 0.f);
        }
    }
    float m = -INFINITY, den = 0.f;
    const int start = eoff[n], end = eoff[n + 1];

    for (int j = start; j < end; ++j) {
        int s = slist[j];
        const float* xlr = xl + (size_t)s * (NH * C) + h * C;
        float4 xv[NQ];
        float ps = 0.f;
        #pragma unroll
        for (int q = 0; q < NQ; ++q) {
            xv[q] = *(const float4*)(xlr + q * 256 + lane * 4);
            float vx = xv[q].x + xr_reg[q].x;
            float vy = xv[q].y + xr_reg[q].y;
            float vz = xv[q].z + xr_reg[q].z;
            float vw = xv[q].w + xr_reg[q].w;
            vx = vx > 0.f ? vx : 0.2f * vx;
            vy = vy > 0.f ? vy : 0.2f * vy;
            vz = vz > 0.f ? vz : 0.2f * vz;
            vw = vw > 0.f ? vw : 0.2f * vw;
            ps = fmaf(vx, att_reg[q].x, ps);
            ps = fmaf(vy, att_reg[q].y, ps);
            ps = fmaf(vz, att_reg[q].z, ps);
            ps = fmaf(vw, att_reg[q].w, ps);
        }
        ps = waveSum(ps);
        float m_new = fmaxf(m, ps);
        float scale = expf(m - m_new);
        float ex = expf(ps - m_new);
        den = den * scale + ex;
        m = m_new;
        #pragma unroll
        for (int q = 0; q < NQ; ++q) {
            acc[q].x = fmaf(ex, xv[q].x, acc[q].x * scale);
            acc[q].y = fmaf(ex, xv[q].y, acc[q].y * scale);
            acc[q].z = fmaf(ex, xv[q].z, acc[q].z * scale);
            acc[q].w = fmaf(ex, xv[q].w, acc[q].w * scale);
        }
    }

    float inv = 1.f / (den + 1e-16f);
    #pragma unroll
    for (int q = 0; q < NQ; ++q) {
        int off = q * 256 + lane * 4;
        float4 r;
        r.x = acc[q].x * inv; r.y = acc[q].y * inv;
        r.z = acc[q].z * inv; r.w = acc[q].w * inv;
        *(float4*)&red[h * C + off] = r;
    }
    __syncthreads();

    int t = threadIdx.x;
    for (int c4 = t; c4 < C / 4; c4 += 256) {
        int c = c4 * 4;
        float4 r0 = *(const float4*)&red[0 * C + c];
        float4 r1 = *(const float4*)&red[1 * C + c];
        float4 r2 = *(const float4*)&red[2 * C + c];
        float4 r3 = *(const float4*)&red[3 * C + c];
        float4 bv = *(const float4*)(bias + c);
        float4 o;
        o.x = fmaxf((r0.x + r1.x + r2.x + r3.x) * 0.25f + bv.x, 0.f);
        o.y = fmaxf((r0.y + r1.y + r2.y + r3.y) * 0.25f + bv.y, 0.f);
        o.z = fmaxf((r0.z + r1.z + r2.z + r3.z) * 0.25f + bv.z, 0.f);
        o.w = fmaxf((r0.w + r1.w + r2.w + r3.w) * 0.25f + bv.w, 0.f);
        *(float4*)(out + (size_t)n * C + c) = o;
    }
}

// ---------------- gate + pool + MLP ----------------

__global__ __launch_bounds__(128) void k_gate(
    const float* __restrict__ x, const float* __restrict__ Wg0,
    const float* __restrict__ bg0, const float* __restrict__ Wg1,
    const float* __restrict__ bg1, float* __restrict__ g)
{
    int n = blockIdx.x;
    int t = threadIdx.x;
    __shared__ float xs[256];
    __shared__ float wsum[2];
    const float* xp = x + (size_t)n * 256;
    xs[t] = xp[t]; xs[t + 128] = xp[t + 128];
    __syncthreads();
    float acc = bg0[t];
    for (int k = 0; k < 256; ++k) acc = fmaf(xs[k], Wg0[k * 128 + t], acc);
    acc = acc > 0.f ? acc : 0.f;
    float prod = acc * Wg1[t];
    prod = waveSum(prod);
    if ((t & 63) == 0) wsum[t >> 6] = prod;
    __syncthreads();
    if (t == 0) g[n] = wsum[0] + wsum[1] + bg1[0];
}

__global__ void k_group_bounds(const int* __restrict__ batch, int* __restrict__ gstart,
                               int* __restrict__ gend) {
    int n = blockIdx.x * 256 + threadIdx.x;
    if (n >= NN) return;
    int b = batch[n];
    if (n == 0 || batch[n - 1] != b) gstart[b] = n;
    if (n == NN - 1 || batch[n + 1] != b) gend[b] = n + 1;
}

// per-group softmax stats: m[g], invden[g]
__global__ __launch_bounds__(256) void k_pool_stats(
    const float* __restrict__ g, const int* __restrict__ gstart,
    const int* __restrict__ gend, float* __restrict__ mOut,
    float* __restrict__ invdenOut)
{
    int gi = blockIdx.x;
    int t = threadIdx.x;
    int s0 = gstart[gi], e0 = gend[gi];
    __shared__ float red[4];
    float mx = -1e30f;
    for (int n = s0 + t; n < e0; n += 256) mx = fmaxf(mx, g[n]);
    float wm = waveMax(mx);
    if ((t & 63) == 0) red[t >> 6] = wm;
    __syncthreads();
    float m = fmaxf(fmaxf(red[0], red[1]), fmaxf(red[2], red[3]));
    __syncthreads();
    float sm = 0.f;
    for (int n = s0 + t; n < e0; n += 256) sm += expf(g[n] - m);
    sm = waveSum(sm);
    if ((t & 63) == 0) red[t >> 6] = sm;
    __syncthreads();
    if (t == 0) {
        float den = red[0] + red[1] + red[2] + red[3] + 1e-16f;
        mOut[gi] = m;
        invdenOut[gi] = 1.f / den;
    }
}

// weighted-sum accumulation, parallel over node chunks; thread t owns channel t
#define PCH 16
__global__ __launch_bounds__(256) void k_pool_acc(
    const float* __restrict__ x, const float* __restrict__ g,
    const int* __restrict__ batch, const float* __restrict__ m,
    const float* __restrict__ invden, float* __restrict__ hpool)
{
    int base = blockIdx.x * PCH;
    int t = threadIdx.x;
    float acc = 0.f;
    int cur = -1;
    for (int i = 0; i < PCH; ++i) {
        int n = base + i;
        if (n >= NN) break;
        int b = batch[n];
        if (b != cur) {
            if (cur >= 0) atomicAdd(&hpool[cur * 256 + t], acc);
            cur = b; acc = 0.f;
        }
        float w = expf(g[n] - m[b]) * invden[b];
        acc = fmaf(w, x[(size_t)n * 256 + t], acc);
    }
    if (cur >= 0) atomicAdd(&hpool[cur * 256 + t], acc);
}

__global__ __launch_bounds__(256) void k_mlp(
    const float* __restrict__ hpool,
    const float* __restrict__ Wm0, const float* __restrict__ bm0,
    const float* __restrict__ Wm1, const float* __restrict__ bm1,
    const float* __restrict__ Wm2, const float* __restrict__ bm2,
    const float* __restrict__ Wm3, const float* __restrict__ bm3,
    const float* __restrict__ Wm4, const float* __restrict__ bm4,
    float* __restrict__ out)
{
    __shared__ float bufA[8 * 256];
    __shared__ float bufB[8 * 128];
    int t = threadIdx.x;
    for (int i = t; i < 8 * 256; i += 256) bufA[i] = hpool[i];
    __syncthreads();
    for (int i = t; i < 8 * 128; i += 256) {
        int r = i >> 7, c = i & 127;
        float acc = bm0[c];
        for (int k = 0; k < 256; ++k) acc = fmaf(bufA[r * 256 + k], Wm0[k * 128 + c], acc);
        bufB[i] = fmaxf(acc, 0.f);
    }
    __syncthreads();
    for (int i = t; i < 8 * 64; i += 256) {
        int r = i >> 6, c = i & 63;
        float acc = bm1[c];
        for (int k = 0; k < 128; ++k) acc = fmaf(bufB[r * 128 + k], Wm1[k * 64 + c], acc);
        bufA[i] = fmaxf(acc, 0.f);
    }
    __syncthreads();
    for (int i = t; i < 8 * 32; i += 256) {
        int r = i >> 5, c = i & 31;
        float acc = bm2[c];
        for (int k = 0; k < 64; ++k) acc = fmaf(bufA[r * 64 + k], Wm2[k * 32 + c], acc);
        bufB[i] = fmaxf(acc, 0.f);
    }
    __syncthreads();
    for (int i = t; i < 8 * 16; i += 256) {
        int r = i >> 4, c = i & 15;
        float acc = bm3[c];
        for (int k = 0; k < 32; ++k) acc = fmaf(bufB[r * 32 + k], Wm3[k * 16 + c], acc);
        bufA[i] = fmaxf(acc, 0.f);
    }
    __syncthreads();
    if (t < 8) {
        float acc = bm4[0];
        for (int k = 0; k < 16; ++k) acc = fmaf(bufA[t * 16 + k], Wm4[k], acc);
        out[t] = acc;
    }
}

// ---------------- host orchestration ----------------

static void run_gat_layer(const float* xin, int K, int C,
                          const float* Wl, const float* bl,
                          const float* Wr, const float* br,
                          const float* att, const float* bias,
                          _Float16* a0p, _Float16* wb0,
                          float* xl, float* xr,
                          const int* eoff, const int* slist,
                          float* xout, hipStream_t stream)
{
    int HC = NH * C;
    int nA = NN * K;
    k_cvtA<<<(nA + 255) / 256, 256, 0, stream>>>(xin, a0p, nA);
    dim3 ggrid(HC / 128, (NN + 127) / 128);
    dim3 tgrid(HC / 32, K / 32);
    k_cvtWT<<<tgrid, 256, 0, stream>>>(Wl, wb0, K, HC);
    gemm_mfma_f16<<<ggrid, 256, 0, stream>>>(a0p, wb0, bl, xl, NN, K, HC);
    k_cvtWT<<<tgrid, 256, 0, stream>>>(Wr, wb0, K, HC);
    gemm_mfma_f16<<<ggrid, 256, 0, stream>>>(a0p, wb0, br, xr, NN, K, HC);

    if (C == 1024)
        k_gat_fused<1024><<<NN, 256, 0, stream>>>(xl, xr, att, eoff, slist, bias, xout);
    else if (C == 512)
        k_gat_fused<512><<<NN, 256, 0, stream>>>(xl, xr, att, eoff, slist, bias, xout);
    else
        k_gat_fused<256><<<NN, 256, 0, stream>>>(xl, xr, att, eoff, slist, bias, xout);
}

extern "C" void kernel_launch(void* const* d_in, const int* in_sizes, int n_in,
                              void* d_out, int out_size, void* d_ws, size_t ws_size,
                              hipStream_t stream) {
    const float* x      = (const float*)d_in[0];
    const int* ei       = (const int*)d_in[1];
    const int* batch    = (const int*)d_in[2];
    const float* Wl1 = (const float*)d_in[3];  const float* bl1 = (const float*)d_in[4];
    const float* Wr1 = (const float*)d_in[5];  const float* br1 = (const float*)d_in[6];
    const float* att1= (const float*)d_in[7];  const float* b1  = (const float*)d_in[8];
    const float* Wl2 = (const float*)d_in[9];  const float* bl2 = (const float*)d_in[10];
    const float* Wr2 = (const float*)d_in[11]; const float* br2 = (const float*)d_in[12];
    const float* att2= (const float*)d_in[13]; const float* b2  = (const float*)d_in[14];
    const float* Wl3 = (const float*)d_in[15]; const float* bl3 = (const float*)d_in[16];
    const float* Wr3 = (const float*)d_in[17]; const float* br3 = (const float*)d_in[18];
    const float* att3= (const float*)d_in[19]; const float* b3  = (const float*)d_in[20];
    const float* Wm0 = (const float*)d_in[21]; const float* bm0 = (const float*)d_in[22];
    const float* Wm1 = (const float*)d_in[23]; const float* bm1 = (const float*)d_in[24];
    const float* Wm2 = (const float*)d_in[25]; const float* bm2 = (const float*)d_in[26];
    const float* Wm3 = (const float*)d_in[27]; const float* bm3 = (const float*)d_in[28];
    const float* Wm4 = (const float*)d_in[29]; const float* bm4 = (const float*)d_in[30];
    const float* Wg0 = (const float*)d_in[31]; const float* bg0 = (const float*)d_in[32];
    const float* Wg1 = (const float*)d_in[33]; const float* bg1 = (const float*)d_in[34];
    float* out = (float*)d_out;

    // workspace carve (float units = 4B); 16B-align the fp16 GEMM buffers
    float* ws = (float*)d_ws;
    size_t o = 0;
    float* xl    = ws + o; o += (size_t)NN * 4096;
    float* xr    = ws + o; o += (size_t)NN * 4096;
    float* x1    = ws + o; o += (size_t)NN * 1024;
    float* x2    = ws + o; o += (size_t)NN * 512;
    float* x3    = ws + o; o += (size_t)NN * 256;
    int* srcA    = (int*)(ws + o); o += NEE;
    int* dstA    = (int*)(ws + o); o += NEE;
    int* cnt     = (int*)(ws + o); o += NN;
    int* eoff    = (int*)(ws + o); o += NN + 1;
    int* cur     = (int*)(ws + o); o += NN;
    int* slist   = (int*)(ws + o); o += NEE;
    float* g     = ws + o; o += NN;
    int* gstart  = (int*)(ws + o); o += NG;
    int* gend    = (int*)(ws + o); o += NG;
    float* gm    = ws + o; o += NG;
    float* ginv  = ws + o; o += NG;
    float* hpool = ws + o; o += NG * 256;
    o = (o + 3) & ~(size_t)3;  // 16B align
    _Float16* a0p = (_Float16*)(ws + o); o += (size_t)NN * 1536 / 2;
    o = (o + 3) & ~(size_t)3;
    _Float16* wb0 = (_Float16*)(ws + o); o += (size_t)1536 * 4096 / 2;

    // build CSR by dst (slist holds src node ids)
    int ebB = (NEE + 255) / 256;
    k_build_edges<<<ebB, 256, 0, stream>>>(ei, srcA, dstA);
    k_zero32<<<(NN + 255) / 256, 256, 0, stream>>>((unsigned int*)cnt, NN);
    k_count<<<ebB, 256, 0, stream>>>(dstA, cnt);
    k_scan<<<1, 256, 0, stream>>>(cnt, eoff, cur);
    k_fill<<<ebB, 256, 0, stream>>>(srcA, dstA, cur, slist);

    // three GATv2 layers
    run_gat_layer(x,  1536, 1024, Wl1, bl1, Wr1, br1, att1, b1,
                  a0p, wb0, xl, xr, eoff, slist, x1, stream);
    run_gat_layer(x1, 1024, 512,  Wl2, bl2, Wr2, br2, att2, b2,
                  a0p, wb0, xl, xr, eoff, slist, x2, stream);
    run_gat_layer(x2, 512,  256,  Wl3, bl3, Wr3, br3, att3, b3,
                  a0p, wb0, xl, xr, eoff, slist, x3, stream);

    // gate + pool + MLP
    k_gate<<<NN, 128, 0, stream>>>(x3, Wg0, bg0, Wg1, bg1, g);
    k_zero32<<<1, 64, 0, stream>>>((unsigned int*)gstart, 2 * NG);
    k_group_bounds<<<(NN + 255) / 256, 256, 0, stream>>>(batch, gstart, gend);
    k_pool_stats<<<NG, 256, 0, stream>>>(g, gstart, gend, gm, ginv);
    k_zero32<<<(NG * 256 + 255) / 256, 256, 0, stream>>>((unsigned int*)hpool, NG * 256);
    k_pool_acc<<<(NN + PCH - 1) / PCH, 256, 0, stream>>>(x3, g, batch, gm, ginv, hpool);
    k_mlp<<<1, 256, 0, stream>>>(hpool, Wm0, bm0, Wm1, bm1, Wm2, bm2,
                                 Wm3, bm3, Wm4, bm4, out);
}

// Round 7
// 773.825 us; speedup vs baseline: 4.2656x; 1.2784x over previous
//
#include <hip/hip_runtime.h>
#include <math.h>

// Problem constants (from reference)
#define NN 5000
#define NNP 5120    // padded rows for GEMM A-operand OOB staging
#define NE 50000
#define NEE 55000   // edges + self loops
#define NG 8
#define NH 4

typedef __attribute__((ext_vector_type(8))) _Float16 half8;
typedef __attribute__((ext_vector_type(4))) _Float16 half4;
typedef __attribute__((ext_vector_type(4))) float floatx4;

// ---------------- utility device functions ----------------

__device__ inline float waveSum(float v) {
    #pragma unroll
    for (int o = 32; o > 0; o >>= 1) v += __shfl_xor(v, o, 64);
    return v;
}
__device__ inline float waveMax(float v) {
    #pragma unroll
    for (int o = 32; o > 0; o >>= 1) v = fmaxf(v, __shfl_xor(v, o, 64));
    return v;
}

// async global->LDS DMA, 16B per lane; lds dest is wave-uniform base + lane*16
__device__ __forceinline__ void gload_lds16(const _Float16* g, _Float16* l) {
    __builtin_amdgcn_global_load_lds(
        (__attribute__((address_space(1))) void*)g,
        (__attribute__((address_space(3))) void*)l,
        16, 0, 0);
}

// ---------------- fp32 -> fp16 conversion ----------------

__global__ void k_cvtA(const float* __restrict__ X, _Float16* __restrict__ A0, int n) {
    int i = blockIdx.x * 256 + threadIdx.x;
    if (i >= n) return;
    A0[i] = (_Float16)X[i];
}

// W (K x M fp32) -> B0 fp16 TRANSPOSED to (M x K)
__global__ __launch_bounds__(256) void k_cvtWT(const float* __restrict__ W,
        _Float16* __restrict__ B0, int K, int M)
{
    __shared__ float tile[32][33];
    int m0 = blockIdx.x * 32, k0 = blockIdx.y * 32;
    int tx = threadIdx.x & 31, ty = threadIdx.x >> 5;
    #pragma unroll
    for (int i = 0; i < 4; ++i)
        tile[ty + 8 * i][tx] = W[(size_t)(k0 + ty + 8 * i) * M + m0 + tx];
    __syncthreads();
    #pragma unroll
    for (int i = 0; i < 4; ++i) {
        int mm = ty + 8 * i, kk = tx;
        B0[(size_t)(m0 + mm) * K + kk + k0] = (_Float16)tile[kk][mm];
    }
}

// ---------------- MFMA fp16 GEMM, dbuf prefetch via global_load_lds ----------
// C(Mrows x N) = A @ B^T + bias; A fp16 (padded rows x K), B fp16 (N x K).
// Output fp16. Double-buffered LDS: DMA for tile t+1 issued BEFORE compute on
// tile t so the end-of-iter barrier's vmcnt drain overlaps with compute.
__global__ __launch_bounds__(256) void gemm_mfma_f16(
    const _Float16* __restrict__ A0, const _Float16* __restrict__ B0,
    const float* __restrict__ bias, _Float16* __restrict__ C,
    int Mrows, int K, int N)
{
    __shared__ __align__(16) _Float16 As[2][128 * 32];
    __shared__ __align__(16) _Float16 Bs[2][128 * 32];

    const int tid = threadIdx.x;
    const int wave = tid >> 6;
    const int lane = tid & 63;
    const int wm = (wave >> 1) * 64;
    const int wn = (wave & 1) * 64;
    const int lm = lane & 15;
    const int kq = (lane >> 4) * 8;
    const int rowBase = blockIdx.y * 128;
    const int colBase = blockIdx.x * 128;

    floatx4 acc[4][4];
    #pragma unroll
    for (int i = 0; i < 4; ++i)
        #pragma unroll
        for (int j = 0; j < 4; ++j)
            acc[i][j] = (floatx4){0.f, 0.f, 0.f, 0.f};

    // staging: wave w owns rows [w*32, w*32+32): 2 DMA issues per matrix
    const int srow = wave * 32 + (lane >> 2);
    const int scol = (lane & 3) * 8;
    const _Float16* gA = A0 + (size_t)(rowBase + srow) * K + scol;
    const _Float16* gB = B0 + (size_t)(colBase + srow) * K + scol;
    const size_t rowSkip = (size_t)16 * K;
    const int lo0 = (wave * 32) * 32;
    const int lo1 = (wave * 32 + 16) * 32;

    // prologue: tile 0 -> buf 0
    gload_lds16(gA, &As[0][lo0]);
    gload_lds16(gA + rowSkip, &As[0][lo1]);
    gload_lds16(gB, &Bs[0][lo0]);
    gload_lds16(gB + rowSkip, &Bs[0][lo1]);
    __syncthreads();

    const int nk = K >> 5;
    for (int t = 0; t < nk; ++t) {
        const int p = t & 1;
        if (t + 1 < nk) {          // prefetch tile t+1 into the other buffer
            const int k1 = (t + 1) << 5;
            gload_lds16(gA + k1, &As[p ^ 1][lo0]);
            gload_lds16(gA + rowSkip + k1, &As[p ^ 1][lo1]);
            gload_lds16(gB + k1, &Bs[p ^ 1][lo0]);
            gload_lds16(gB + rowSkip + k1, &Bs[p ^ 1][lo1]);
        }
        half8 a0[4], b0[4];
        #pragma unroll
        for (int i = 0; i < 4; ++i) {
            a0[i] = *(const half8*)&As[p][(wm + i * 16 + lm) * 32 + kq];
            b0[i] = *(const half8*)&Bs[p][(wn + i * 16 + lm) * 32 + kq];
        }
        #pragma unroll
        for (int i = 0; i < 4; ++i)
            #pragma unroll
            for (int j = 0; j < 4; ++j)
                acc[i][j] = __builtin_amdgcn_mfma_f32_16x16x32_f16(a0[i], b0[j], acc[i][j], 0, 0, 0);
        __syncthreads();
    }

    const int cq = (lane >> 4) * 4;
    #pragma unroll
    for (int j = 0; j < 4; ++j) {
        int col = colBase + wn + j * 16 + lm;
        float bv = bias[col];
        #pragma unroll
        for (int i = 0; i < 4; ++i) {
            #pragma unroll
            for (int r = 0; r < 4; ++r) {
                int grow = rowBase + wm + i * 16 + cq + r;
                if (grow < Mrows)
                    C[(size_t)grow * N + col] = (_Float16)(acc[i][j][r] + bv);
            }
        }
    }
}

// ---------------- CSR build ----------------

__global__ void k_build_edges(const int* __restrict__ ei, int* __restrict__ src,
                              int* __restrict__ dst) {
    int i = blockIdx.x * 256 + threadIdx.x;
    if (i < NE) { src[i] = ei[i]; dst[i] = ei[NE + i]; }
    else if (i < NEE) { src[i] = i - NE; dst[i] = i - NE; }
}

__global__ void k_zero32(unsigned int* __restrict__ p, int n) {
    int i = blockIdx.x * 256 + threadIdx.x;
    if (i < n) p[i] = 0u;
}

__global__ void k_count(const int* __restrict__ dst, int* __restrict__ cnt) {
    int i = blockIdx.x * 256 + threadIdx.x;
    if (i < NEE) atomicAdd(&cnt[dst[i]], 1);
}

__global__ __launch_bounds__(256) void k_scan(const int* __restrict__ cnt,
                                              int* __restrict__ off, int* __restrict__ cur) {
    __shared__ int partial[256];
    __shared__ int ppre[257];
    int t = threadIdx.x;
    const int chunk = (NN + 255) / 256;
    int lo = t * chunk, hi = min(NN, (t + 1) * chunk);
    int s = 0;
    for (int i = lo; i < hi; ++i) s += cnt[i];
    partial[t] = s;
    __syncthreads();
    if (t == 0) {
        int acc = 0;
        for (int i = 0; i < 256; ++i) { ppre[i] = acc; acc += partial[i]; }
        ppre[256] = acc;
    }
    __syncthreads();
    int acc = ppre[t];
    for (int i = lo; i < hi; ++i) { off[i] = acc; cur[i] = acc; acc += cnt[i]; }
    if (t == 0) off[NN] = ppre[256];
}

__global__ void k_fill(const int* __restrict__ src, const int* __restrict__ dst,
                       int* __restrict__ cur, int* __restrict__ slist) {
    int e = blockIdx.x * 256 + threadIdx.x;
    if (e < NEE) { int p = atomicAdd(&cur[dst[e]], 1); slist[p] = src[e]; }
}

// ---------------- fused GATv2 edge pipeline (fp16 activations) -------------
template<int C>
__global__ __launch_bounds__(256) void k_gat_fused(
    const _Float16* __restrict__ xl, const _Float16* __restrict__ xr,
    const float* __restrict__ att, const int* __restrict__ eoff,
    const int* __restrict__ slist, const float* __restrict__ bias,
    _Float16* __restrict__ out)
{
    constexpr int NQ = C / 256;
    __shared__ float red[NH * C];
    const int n = blockIdx.x;
    const int h = threadIdx.x >> 6;
    const int lane = threadIdx.x & 63;

    float4 xr_reg[NQ], att_reg[NQ], acc[NQ];
    {
        const _Float16* xrow = xr + (size_t)n * (NH * C) + h * C;
        const float* ah   = att + h * C;
        #pragma unroll
        for (int q = 0; q < NQ; ++q) {
            int off = q * 256 + lane * 4;
            half4 hv = *(const half4*)(xrow + off);
            xr_reg[q] = make_float4((float)hv[0], (float)hv[1], (float)hv[2], (float)hv[3]);
            att_reg[q] = *(const float4*)(ah + off);
            acc[q] = make_float4(0.f, 0.f, 0.f, 0.f);
        }
    }
    float m = -INFINITY, den = 0.f;
    const int start = eoff[n], end = eoff[n + 1];

    for (int j = start; j < end; ++j) {
        int s = slist[j];
        const _Float16* xlr = xl + (size_t)s * (NH * C) + h * C;
        float4 xv[NQ];
        float ps = 0.f;
        #pragma unroll
        for (int q = 0; q < NQ; ++q) {
            half4 hv = *(const half4*)(xlr + q * 256 + lane * 4);
            xv[q] = make_float4((float)hv[0], (float)hv[1], (float)hv[2], (float)hv[3]);
            float vx = xv[q].x + xr_reg[q].x;
            float vy = xv[q].y + xr_reg[q].y;
            float vz = xv[q].z + xr_reg[q].z;
            float vw = xv[q].w + xr_reg[q].w;
            vx = vx > 0.f ? vx : 0.2f * vx;
            vy = vy > 0.f ? vy : 0.2f * vy;
            vz = vz > 0.f ? vz : 0.2f * vz;
            vw = vw > 0.f ? vw : 0.2f * vw;
            ps = fmaf(vx, att_reg[q].x, ps);
            ps = fmaf(vy, att_reg[q].y, ps);
            ps = fmaf(vz, att_reg[q].z, ps);
            ps = fmaf(vw, att_reg[q].w, ps);
        }
        ps = waveSum(ps);
        float m_new = fmaxf(m, ps);
        float scale = expf(m - m_new);
        float ex = expf(ps - m_new);
        den = den * scale + ex;
        m = m_new;
        #pragma unroll
        for (int q = 0; q < NQ; ++q) {
            acc[q].x = fmaf(ex, xv[q].x, acc[q].x * scale);
            acc[q].y = fmaf(ex, xv[q].y, acc[q].y * scale);
            acc[q].z = fmaf(ex, xv[q].z, acc[q].z * scale);
            acc[q].w = fmaf(ex, xv[q].w, acc[q].w * scale);
        }
    }

    float inv = 1.f / (den + 1e-16f);
    #pragma unroll
    for (int q = 0; q < NQ; ++q) {
        int off = q * 256 + lane * 4;
        float4 r;
        r.x = acc[q].x * inv; r.y = acc[q].y * inv;
        r.z = acc[q].z * inv; r.w = acc[q].w * inv;
        *(float4*)&red[h * C + off] = r;
    }
    __syncthreads();

    int t = threadIdx.x;
    for (int c4 = t; c4 < C / 4; c4 += 256) {
        int c = c4 * 4;
        float4 r0 = *(const float4*)&red[0 * C + c];
        float4 r1 = *(const float4*)&red[1 * C + c];
        float4 r2 = *(const float4*)&red[2 * C + c];
        float4 r3 = *(const float4*)&red[3 * C + c];
        float4 bv = *(const float4*)(bias + c);
        half4 o;
        o[0] = (_Float16)fmaxf((r0.x + r1.x + r2.x + r3.x) * 0.25f + bv.x, 0.f);
        o[1] = (_Float16)fmaxf((r0.y + r1.y + r2.y + r3.y) * 0.25f + bv.y, 0.f);
        o[2] = (_Float16)fmaxf((r0.z + r1.z + r2.z + r3.z) * 0.25f + bv.z, 0.f);
        o[3] = (_Float16)fmaxf((r0.w + r1.w + r2.w + r3.w) * 0.25f + bv.w, 0.f);
        *(half4*)(out + (size_t)n * C + c) = o;
    }
}

// ---------------- gate + pool + MLP ----------------

__global__ __launch_bounds__(128) void k_gate(
    const _Float16* __restrict__ x, const float* __restrict__ Wg0,
    const float* __restrict__ bg0, const float* __restrict__ Wg1,
    const float* __restrict__ bg1, float* __restrict__ g)
{
    int n = blockIdx.x;
    int t = threadIdx.x;
    __shared__ float xs[256];
    __shared__ float wsum[2];
    const _Float16* xp = x + (size_t)n * 256;
    xs[t] = (float)xp[t]; xs[t + 128] = (float)xp[t + 128];
    __syncthreads();
    float acc = bg0[t];
    for (int k = 0; k < 256; ++k) acc = fmaf(xs[k], Wg0[k * 128 + t], acc);
    acc = acc > 0.f ? acc : 0.f;
    float prod = acc * Wg1[t];
    prod = waveSum(prod);
    if ((t & 63) == 0) wsum[t >> 6] = prod;
    __syncthreads();
    if (t == 0) g[n] = wsum[0] + wsum[1] + bg1[0];
}

__global__ void k_group_bounds(const int* __restrict__ batch, int* __restrict__ gstart,
                               int* __restrict__ gend) {
    int n = blockIdx.x * 256 + threadIdx.x;
    if (n >= NN) return;
    int b = batch[n];
    if (n == 0 || batch[n - 1] != b) gstart[b] = n;
    if (n == NN - 1 || batch[n + 1] != b) gend[b] = n + 1;
}

// per-group softmax stats: m[g], invden[g]
__global__ __launch_bounds__(256) void k_pool_stats(
    const float* __restrict__ g, const int* __restrict__ gstart,
    const int* __restrict__ gend, float* __restrict__ mOut,
    float* __restrict__ invdenOut)
{
    int gi = blockIdx.x;
    int t = threadIdx.x;
    int s0 = gstart[gi], e0 = gend[gi];
    __shared__ float red[4];
    float mx = -1e30f;
    for (int n = s0 + t; n < e0; n += 256) mx = fmaxf(mx, g[n]);
    float wm = waveMax(mx);
    if ((t & 63) == 0) red[t >> 6] = wm;
    __syncthreads();
    float m = fmaxf(fmaxf(red[0], red[1]), fmaxf(red[2], red[3]));
    __syncthreads();
    float sm = 0.f;
    for (int n = s0 + t; n < e0; n += 256) sm += expf(g[n] - m);
    sm = waveSum(sm);
    if ((t & 63) == 0) red[t >> 6] = sm;
    __syncthreads();
    if (t == 0) {
        float den = red[0] + red[1] + red[2] + red[3] + 1e-16f;
        mOut[gi] = m;
        invdenOut[gi] = 1.f / den;
    }
}

// weighted-sum accumulation, parallel over node chunks; thread t owns channel t
#define PCH 16
__global__ __launch_bounds__(256) void k_pool_acc(
    const _Float16* __restrict__ x, const float* __restrict__ g,
    const int* __restrict__ batch, const float* __restrict__ m,
    const float* __restrict__ invden, float* __restrict__ hpool)
{
    int base = blockIdx.x * PCH;
    int t = threadIdx.x;
    float acc = 0.f;
    int cur = -1;
    for (int i = 0; i < PCH; ++i) {
        int n = base + i;
        if (n >= NN) break;
        int b = batch[n];
        if (b != cur) {
            if (cur >= 0) atomicAdd(&hpool[cur * 256 + t], acc);
            cur = b; acc = 0.f;
        }
        float w = expf(g[n] - m[b]) * invden[b];
        acc = fmaf(w, (float)x[(size_t)n * 256 + t], acc);
    }
    if (cur >= 0) atomicAdd(&hpool[cur * 256 + t], acc);
}

__global__ __launch_bounds__(256) void k_mlp(
    const float* __restrict__ hpool,
    const float* __restrict__ Wm0, const float* __restrict__ bm0,
    const float* __restrict__ Wm1, const float* __restrict__ bm1,
    const float* __restrict__ Wm2, const float* __restrict__ bm2,
    const float* __restrict__ Wm3, const float* __restrict__ bm3,
    const float* __restrict__ Wm4, const float* __restrict__ bm4,
    float* __restrict__ out)
{
    __shared__ float bufA[8 * 256];
    __shared__ float bufB[8 * 128];
    int t = threadIdx.x;
    for (int i = t; i < 8 * 256; i += 256) bufA[i] = hpool[i];
    __syncthreads();
    for (int i = t; i < 8 * 128; i += 256) {
        int r = i >> 7, c = i & 127;
        float acc = bm0[c];
        for (int k = 0; k < 256; ++k) acc = fmaf(bufA[r * 256 + k], Wm0[k * 128 + c], acc);
        bufB[i] = fmaxf(acc, 0.f);
    }
    __syncthreads();
    for (int i = t; i < 8 * 64; i += 256) {
        int r = i >> 6, c = i & 63;
        float acc = bm1[c];
        for (int k = 0; k < 128; ++k) acc = fmaf(bufB[r * 128 + k], Wm1[k * 64 + c], acc);
        bufA[i] = fmaxf(acc, 0.f);
    }
    __syncthreads();
    for (int i = t; i < 8 * 32; i += 256) {
        int r = i >> 5, c = i & 31;
        float acc = bm2[c];
        for (int k = 0; k < 64; ++k) acc = fmaf(bufA[r * 64 + k], Wm2[k * 32 + c], acc);
        bufB[i] = fmaxf(acc, 0.f);
    }
    __syncthreads();
    for (int i = t; i < 8 * 16; i += 256) {
        int r = i >> 4, c = i & 15;
        float acc = bm3[c];
        for (int k = 0; k < 32; ++k) acc = fmaf(bufB[r * 32 + k], Wm3[k * 16 + c], acc);
        bufA[i] = fmaxf(acc, 0.f);
    }
    __syncthreads();
    if (t < 8) {
        float acc = bm4[0];
        for (int k = 0; k < 16; ++k) acc = fmaf(bufA[t * 16 + k], Wm4[k], acc);
        out[t] = acc;
    }
}

// ---------------- host orchestration ----------------

static void run_gat_layer(const _Float16* ain, int K, int C,
                          const float* Wl, const float* bl,
                          const float* Wr, const float* br,
                          const float* att, const float* bias,
                          _Float16* wb0, _Float16* xl, _Float16* xr,
                          const int* eoff, const int* slist,
                          _Float16* xout, hipStream_t stream)
{
    int HC = NH * C;
    dim3 ggrid(HC / 128, NNP / 128);
    dim3 tgrid(HC / 32, K / 32);
    k_cvtWT<<<tgrid, 256, 0, stream>>>(Wl, wb0, K, HC);
    gemm_mfma_f16<<<ggrid, 256, 0, stream>>>(ain, wb0, bl, xl, NN, K, HC);
    k_cvtWT<<<tgrid, 256, 0, stream>>>(Wr, wb0, K, HC);
    gemm_mfma_f16<<<ggrid, 256, 0, stream>>>(ain, wb0, br, xr, NN, K, HC);

    if (C == 1024)
        k_gat_fused<1024><<<NN, 256, 0, stream>>>(xl, xr, att, eoff, slist, bias, xout);
    else if (C == 512)
        k_gat_fused<512><<<NN, 256, 0, stream>>>(xl, xr, att, eoff, slist, bias, xout);
    else
        k_gat_fused<256><<<NN, 256, 0, stream>>>(xl, xr, att, eoff, slist, bias, xout);
}

extern "C" void kernel_launch(void* const* d_in, const int* in_sizes, int n_in,
                              void* d_out, int out_size, void* d_ws, size_t ws_size,
                              hipStream_t stream) {
    const float* x      = (const float*)d_in[0];
    const int* ei       = (const int*)d_in[1];
    const int* batch    = (const int*)d_in[2];
    const float* Wl1 = (const float*)d_in[3];  const float* bl1 = (const float*)d_in[4];
    const float* Wr1 = (const float*)d_in[5];  const float* br1 = (const float*)d_in[6];
    const float* att1= (const float*)d_in[7];  const float* b1  = (const float*)d_in[8];
    const float* Wl2 = (const float*)d_in[9];  const float* bl2 = (const float*)d_in[10];
    const float* Wr2 = (const float*)d_in[11]; const float* br2 = (const float*)d_in[12];
    const float* att2= (const float*)d_in[13]; const float* b2  = (const float*)d_in[14];
    const float* Wl3 = (const float*)d_in[15]; const float* bl3 = (const float*)d_in[16];
    const float* Wr3 = (const float*)d_in[17]; const float* br3 = (const float*)d_in[18];
    const float* att3= (const float*)d_in[19]; const float* b3  = (const float*)d_in[20];
    const float* Wm0 = (const float*)d_in[21]; const float* bm0 = (const float*)d_in[22];
    const float* Wm1 = (const float*)d_in[23]; const float* bm1 = (const float*)d_in[24];
    const float* Wm2 = (const float*)d_in[25]; const float* bm2 = (const float*)d_in[26];
    const float* Wm3 = (const float*)d_in[27]; const float* bm3 = (const float*)d_in[28];
    const float* Wm4 = (const float*)d_in[29]; const float* bm4 = (const float*)d_in[30];
    const float* Wg0 = (const float*)d_in[31]; const float* bg0 = (const float*)d_in[32];
    const float* Wg1 = (const float*)d_in[33]; const float* bg1 = (const float*)d_in[34];
    float* out = (float*)d_out;

    // workspace carve (float units = 4B); fp16 buffers 16B-aligned, padded rows
    float* ws = (float*)d_ws;
    size_t o = 0;
    _Float16* xl  = (_Float16*)(ws + o); o += (size_t)NNP * 4096 / 2;
    _Float16* xr  = (_Float16*)(ws + o); o += (size_t)NNP * 4096 / 2;
    _Float16* x1  = (_Float16*)(ws + o); o += (size_t)NNP * 1024 / 2;
    _Float16* x2  = (_Float16*)(ws + o); o += (size_t)NNP * 512 / 2;
    _Float16* x3  = (_Float16*)(ws + o); o += (size_t)NNP * 256 / 2;
    _Float16* a0p = (_Float16*)(ws + o); o += (size_t)NNP * 1536 / 2;
    _Float16* wb0 = (_Float16*)(ws + o); o += (size_t)1536 * 4096 / 2;
    int* srcA    = (int*)(ws + o); o += NEE;
    int* dstA    = (int*)(ws + o); o += NEE;
    int* cnt     = (int*)(ws + o); o += NN;
    int* eoff    = (int*)(ws + o); o += NN + 1;
    int* cur     = (int*)(ws + o); o += NN;
    int* slist   = (int*)(ws + o); o += NEE;
    float* g     = ws + o; o += NN;
    int* gstart  = (int*)(ws + o); o += NG;
    int* gend    = (int*)(ws + o); o += NG;
    float* gm    = ws + o; o += NG;
    float* ginv  = ws + o; o += NG;
    float* hpool = ws + o; o += NG * 256;

    // build CSR by dst (slist holds src node ids)
    int ebB = (NEE + 255) / 256;
    k_build_edges<<<ebB, 256, 0, stream>>>(ei, srcA, dstA);
    k_zero32<<<(NN + 255) / 256, 256, 0, stream>>>((unsigned int*)cnt, NN);
    k_count<<<ebB, 256, 0, stream>>>(dstA, cnt);
    k_scan<<<1, 256, 0, stream>>>(cnt, eoff, cur);
    k_fill<<<ebB, 256, 0, stream>>>(srcA, dstA, cur, slist);

    // layer-1 input -> fp16 (only conversion needed; later layers emit fp16)
    int nA = NN * 1536;
    k_cvtA<<<(nA + 255) / 256, 256, 0, stream>>>(x, a0p, nA);

    // three GATv2 layers
    run_gat_layer(a0p, 1536, 1024, Wl1, bl1, Wr1, br1, att1, b1,
                  wb0, xl, xr, eoff, slist, x1, stream);
    run_gat_layer(x1,  1024, 512,  Wl2, bl2, Wr2, br2, att2, b2,
                  wb0, xl, xr, eoff, slist, x2, stream);
    run_gat_layer(x2,  512,  256,  Wl3, bl3, Wr3, br3, att3, b3,
                  wb0, xl, xr, eoff, slist, x3, stream);

    // gate + pool + MLP
    k_gate<<<NN, 128, 0, stream>>>(x3, Wg0, bg0, Wg1, bg1, g);
    k_zero32<<<1, 64, 0, stream>>>((unsigned int*)gstart, 2 * NG);
    k_group_bounds<<<(NN + 255) / 256, 256, 0, stream>>>(batch, gstart, gend);
    k_pool_stats<<<NG, 256, 0, stream>>>(g, gstart, gend, gm, ginv);
    k_zero32<<<(NG * 256 + 255) / 256, 256, 0, stream>>>((unsigned int*)hpool, NG * 256);
    k_pool_acc<<<(NN + PCH - 1) / PCH, 256, 0, stream>>>(x3, g, batch, gm, ginv, hpool);
    k_mlp<<<1, 256, 0, stream>>>(hpool, Wm0, bm0, Wm1, bm1, Wm2, bm2,
                                 Wm3, bm3, Wm4, bm4, out);
}